// Round 1
// baseline (2271.099 us; speedup 1.0000x reference)
//
#include <hip/hip_runtime.h>

#define NN 20000
#define NE 160000
#define HD 64
#define TT 3

// ---------------- init: pos_out[0]=world_pos, vel_out[0]=velocity ----------------
__global__ __launch_bounds__(256) void k_init_out(const float* __restrict__ wp,
    const float* __restrict__ vel, float* __restrict__ PO, float* __restrict__ VO) {
  int i = blockIdx.x * 256 + threadIdx.x;
  if (i < NN * 3) { PO[i] = wp[i]; VO[i] = vel[i]; }
}

// ---------------- static node-encoder part: h_preT[j][n] = b1[j] + other(n)·W1[3:13,j] ----------------
__global__ __launch_bounds__(256) void k_hpre(const float* __restrict__ youngs,
    const float* __restrict__ onehot, const float* __restrict__ ym, const float* __restrict__ ys,
    const float* __restrict__ w_ne1, const float* __restrict__ b_ne1, float* __restrict__ h_preT) {
  int idx = blockIdx.x * 256 + threadIdx.x;
  if (idx >= NN * HD) return;
  int n = idx % NN, j = idx / NN;
  float a = b_ne1[j];
  float yn = (youngs[n] - ym[0]) / ys[0];
  a += yn * w_ne1[3 * HD + j];
#pragma unroll
  for (int k = 0; k < 9; k++) a += onehot[n * 9 + k] * w_ne1[(4 + k) * HD + j];
  h_preT[(size_t)j * NN + n] = a;
}

// ---------------- static edge encoder + em_pre (once) ----------------
__global__ __launch_bounds__(256) void k_edge_static(const float* __restrict__ eattr,
    const float* __restrict__ emean, const float* __restrict__ estd,
    const float* __restrict__ w_ee1, const float* __restrict__ b_ee1,
    const float* __restrict__ w_ee2, const float* __restrict__ b_ee2,
    const float* __restrict__ w_em1, const float* __restrict__ b_em1,
    float* __restrict__ e_enc, float* __restrict__ em_pre) {
  __shared__ float s_w1[4 * HD];
  __shared__ float s_w2[HD * HD];
  __shared__ float s_wm[HD * HD];
  __shared__ float s_b1[HD], s_b2[HD], s_bm[HD];
  __shared__ float s_m[4], s_s[4];
  int tid = threadIdx.x;
  for (int i = tid; i < 4 * HD; i += 256) s_w1[i] = w_ee1[i];
  for (int i = tid; i < HD * HD; i += 256) { s_w2[i] = w_ee2[i]; s_wm[i] = w_em1[i]; }
  if (tid < HD) { s_b1[tid] = b_ee1[tid]; s_b2[tid] = b_ee2[tid]; s_bm[tid] = b_em1[tid]; }
  if (tid < 4) { s_m[tid] = emean[tid]; s_s[tid] = estd[tid]; }
  __syncthreads();
  int e = blockIdx.x * 256 + tid;
  if (e >= NE) return;
  float x0 = (eattr[e * 4 + 0] - s_m[0]) / s_s[0];
  float x1 = (eattr[e * 4 + 1] - s_m[1]) / s_s[1];
  float x2 = (eattr[e * 4 + 2] - s_m[2]) / s_s[2];
  float x3 = (eattr[e * 4 + 3] - s_m[3]) / s_s[3];
  float hid[HD];
#pragma unroll
  for (int j = 0; j < HD; j++) {
    float a = s_b1[j] + x0 * s_w1[j] + x1 * s_w1[HD + j] + x2 * s_w1[2 * HD + j] + x3 * s_w1[3 * HD + j];
    hid[j] = fmaxf(a, 0.f);
  }
  float enc[HD];
#pragma unroll
  for (int j4 = 0; j4 < 16; j4++) {
    float a0 = s_b2[4 * j4], a1 = s_b2[4 * j4 + 1], a2 = s_b2[4 * j4 + 2], a3 = s_b2[4 * j4 + 3];
#pragma unroll
    for (int k = 0; k < HD; k++) {
      float x = hid[k];
      const float* wr = &s_w2[k * HD + 4 * j4];
      a0 += x * wr[0]; a1 += x * wr[1]; a2 += x * wr[2]; a3 += x * wr[3];
    }
    enc[4 * j4] = a0; enc[4 * j4 + 1] = a1; enc[4 * j4 + 2] = a2; enc[4 * j4 + 3] = a3;
    float4 o = {a0, a1, a2, a3};
    ((float4*)(e_enc + (size_t)e * HD))[j4] = o;
  }
#pragma unroll
  for (int j4 = 0; j4 < 16; j4++) {
    float a0 = s_bm[4 * j4], a1 = s_bm[4 * j4 + 1], a2 = s_bm[4 * j4 + 2], a3 = s_bm[4 * j4 + 3];
#pragma unroll
    for (int k = 0; k < HD; k++) {
      float x = enc[k];
      const float* wr = &s_wm[k * HD + 4 * j4];
      a0 += x * wr[0]; a1 += x * wr[1]; a2 += x * wr[2]; a3 += x * wr[3];
    }
    float4 o = {a0, a1, a2, a3};
    ((float4*)(em_pre + (size_t)e * HD))[j4] = o;
  }
}

// ---------------- CSR build ----------------
__global__ __launch_bounds__(256) void k_zero2(int* __restrict__ a, int* __restrict__ b) {
  int i = blockIdx.x * 256 + threadIdx.x;
  if (i < NN) { a[i] = 0; b[i] = 0; }
}

__global__ __launch_bounds__(256) void k_count(const int* __restrict__ eidx, int* __restrict__ counts) {
  int e = blockIdx.x * 256 + threadIdx.x;
  if (e < NE) atomicAdd(&counts[eidx[NE + e]], 1);
}

__global__ __launch_bounds__(256) void k_scan(const int* __restrict__ counts, int* __restrict__ row_ptr) {
  __shared__ int part[256];
  int tid = threadIdx.x;
  const int per = (NN + 255) / 256;
  int base = tid * per;
  int s = 0;
  for (int i = 0; i < per; i++) { int idx = base + i; if (idx < NN) s += counts[idx]; }
  part[tid] = s;
  __syncthreads();
  if (tid == 0) {
    int run = 0;
    for (int i = 0; i < 256; i++) { int v = part[i]; part[i] = run; run += v; }
  }
  __syncthreads();
  int run = part[tid];
  for (int i = 0; i < per; i++) {
    int idx = base + i;
    if (idx < NN) { row_ptr[idx] = run; run += counts[idx]; }
  }
  if (tid == 255) row_ptr[NN] = run;
}

__global__ __launch_bounds__(256) void k_place(const int* __restrict__ eidx,
    const int* __restrict__ row_ptr, int* __restrict__ fill, int* __restrict__ slot) {
  int e = blockIdx.x * 256 + threadIdx.x;
  if (e >= NE) return;
  int d = eidx[NE + e];
  int f = atomicAdd(&fill[d], 1);
  slot[e] = row_ptr[d] + f;
}

// ---------------- per-deriv: node encoder ----------------
__global__ __launch_bounds__(256) void k_node_enc(const float* __restrict__ vel,
    const float* __restrict__ vmean, const float* __restrict__ vstd,
    const float* __restrict__ w_ne1, const float* __restrict__ h_preT,
    const float* __restrict__ w_ne2, const float* __restrict__ b_ne2, float* __restrict__ h) {
  __shared__ float s_w1[3 * HD];
  __shared__ float s_w2[HD * HD];
  __shared__ float s_b2[HD];
  __shared__ float s_vm[3], s_vs[3];
  int tid = threadIdx.x;
  for (int i = tid; i < 3 * HD; i += 256) s_w1[i] = w_ne1[i];
  for (int i = tid; i < HD * HD; i += 256) s_w2[i] = w_ne2[i];
  if (tid < HD) s_b2[tid] = b_ne2[tid];
  if (tid < 3) { s_vm[tid] = vmean[tid]; s_vs[tid] = vstd[tid]; }
  __syncthreads();
  int n = blockIdx.x * 256 + tid;
  if (n >= NN) return;
  float v0 = (vel[n * 3 + 0] - s_vm[0]) / s_vs[0];
  float v1 = (vel[n * 3 + 1] - s_vm[1]) / s_vs[1];
  float v2 = (vel[n * 3 + 2] - s_vm[2]) / s_vs[2];
  float hid[HD];
#pragma unroll
  for (int j = 0; j < HD; j++) {
    float a = h_preT[(size_t)j * NN + n] + v0 * s_w1[j] + v1 * s_w1[HD + j] + v2 * s_w1[2 * HD + j];
    hid[j] = fmaxf(a, 0.f);
  }
  float4* op = (float4*)(h + (size_t)n * HD);
#pragma unroll
  for (int j4 = 0; j4 < 16; j4++) {
    float a0 = s_b2[4 * j4], a1 = s_b2[4 * j4 + 1], a2 = s_b2[4 * j4 + 2], a3 = s_b2[4 * j4 + 3];
#pragma unroll
    for (int k = 0; k < HD; k++) {
      float x = hid[k];
      const float* wr = &s_w2[k * HD + 4 * j4];
      a0 += x * wr[0]; a1 += x * wr[1]; a2 += x * wr[2]; a3 += x * wr[3];
    }
    float4 o = {a0, a1, a2, a3};
    op[j4] = o;
  }
}

// ---------------- per-deriv: edge message MLP (hot kernel), permuted store ----------------
__global__ __launch_bounds__(256) void k_edge_msg(const int* __restrict__ eidx,
    const int* __restrict__ slot, const float* __restrict__ h,
    const float* __restrict__ em_pre, const float* __restrict__ e_enc,
    const float* __restrict__ w_em1, const float* __restrict__ w_em2,
    const float* __restrict__ b_em2, float* __restrict__ emsg) {
  __shared__ float s_w1[128 * HD];  // rows 64..191 of w_em1 (src, dst parts), 32KB
  __shared__ float s_w2[HD * HD];   // 16KB
  __shared__ float s_b2[HD];
  int tid = threadIdx.x;
  for (int i = tid; i < 128 * HD; i += 256) s_w1[i] = w_em1[64 * HD + i];
  for (int i = tid; i < HD * HD; i += 256) s_w2[i] = w_em2[i];
  if (tid < HD) s_b2[tid] = b_em2[tid];
  __syncthreads();
  int e = blockIdx.x * 256 + tid;
  if (e >= NE) return;
  int src = eidx[e], dst = eidx[NE + e];
  float hid[HD];
  const float4* ep = (const float4*)(em_pre + (size_t)e * HD);
#pragma unroll
  for (int j4 = 0; j4 < 16; j4++) {
    float4 v = ep[j4];
    hid[4 * j4] = v.x; hid[4 * j4 + 1] = v.y; hid[4 * j4 + 2] = v.z; hid[4 * j4 + 3] = v.w;
  }
  const float4* hs = (const float4*)(h + (size_t)src * HD);
#pragma unroll
  for (int k4 = 0; k4 < 16; k4++) {
    float4 v = hs[k4];
    float xs[4] = {v.x, v.y, v.z, v.w};
#pragma unroll
    for (int kk = 0; kk < 4; kk++) {
      float x = xs[kk];
      const float* wr = &s_w1[(4 * k4 + kk) * HD];
#pragma unroll
      for (int j = 0; j < HD; j++) hid[j] += x * wr[j];
    }
  }
  const float4* hdp = (const float4*)(h + (size_t)dst * HD);
#pragma unroll
  for (int k4 = 0; k4 < 16; k4++) {
    float4 v = hdp[k4];
    float xs[4] = {v.x, v.y, v.z, v.w};
#pragma unroll
    for (int kk = 0; kk < 4; kk++) {
      float x = xs[kk];
      const float* wr = &s_w1[(64 + 4 * k4 + kk) * HD];
#pragma unroll
      for (int j = 0; j < HD; j++) hid[j] += x * wr[j];
    }
  }
#pragma unroll
  for (int j = 0; j < HD; j++) hid[j] = fmaxf(hid[j], 0.f);
  const float4* ee = (const float4*)(e_enc + (size_t)e * HD);
  float4* outp = (float4*)(emsg + (size_t)slot[e] * HD);
#pragma unroll
  for (int j4 = 0; j4 < 16; j4++) {
    float a0 = s_b2[4 * j4], a1 = s_b2[4 * j4 + 1], a2 = s_b2[4 * j4 + 2], a3 = s_b2[4 * j4 + 3];
#pragma unroll
    for (int k = 0; k < HD; k++) {
      float x = hid[k];
      const float* wr = &s_w2[k * HD + 4 * j4];
      a0 += x * wr[0]; a1 += x * wr[1]; a2 += x * wr[2]; a3 += x * wr[3];
    }
    float4 r = ee[j4];
    float4 o = {r.x + a0, r.y + a1, r.z + a2, r.w + a3};
    outp[j4] = o;
  }
}

// ---------------- per-deriv: aggregation (wave per node, lane per channel) ----------------
__global__ __launch_bounds__(256) void k_agg(const int* __restrict__ row_ptr,
    const float* __restrict__ emsg, float* __restrict__ agg) {
  int lane = threadIdx.x & 63;
  int wid = threadIdx.x >> 6;
  int n = blockIdx.x * 4 + wid;
  if (n >= NN) return;
  int b = row_ptr[n], e = row_ptr[n + 1];
  float s = 0.f;
  for (int i = b; i < e; i++) s += emsg[(size_t)i * HD + lane];
  agg[(size_t)n * HD + lane] = s;
}

// ---------------- per-deriv: node update + decoder (fused) ----------------
__global__ __launch_bounds__(256) void k_node_upd(const float* __restrict__ h,
    const float* __restrict__ agg,
    const float* __restrict__ w_nm1, const float* __restrict__ b_nm1,
    const float* __restrict__ w_nm2, const float* __restrict__ b_nm2,
    const float* __restrict__ w_dec1, const float* __restrict__ b_dec1,
    const float* __restrict__ w_dec2, const float* __restrict__ b_dec2,
    const float* __restrict__ amean, const float* __restrict__ astd, float* __restrict__ accv) {
  __shared__ float s_w1[128 * HD];  // 32KB
  __shared__ float s_w2[HD * HD];   // 16KB; decoder weights read from global (uniform -> s_load)
  __shared__ float s_b1[HD], s_b2[HD];
  int tid = threadIdx.x;
  for (int i = tid; i < 128 * HD; i += 256) s_w1[i] = w_nm1[i];
  for (int i = tid; i < HD * HD; i += 256) s_w2[i] = w_nm2[i];
  if (tid < HD) { s_b1[tid] = b_nm1[tid]; s_b2[tid] = b_nm2[tid]; }
  __syncthreads();
  int n = blockIdx.x * 256 + tid;
  if (n >= NN) return;
  float hrow[HD];
  const float4* hp = (const float4*)(h + (size_t)n * HD);
#pragma unroll
  for (int j4 = 0; j4 < 16; j4++) {
    float4 v = hp[j4];
    hrow[4 * j4] = v.x; hrow[4 * j4 + 1] = v.y; hrow[4 * j4 + 2] = v.z; hrow[4 * j4 + 3] = v.w;
  }
  float hid[HD];
#pragma unroll
  for (int j = 0; j < HD; j++) hid[j] = s_b1[j];
#pragma unroll
  for (int k = 0; k < HD; k++) {
    float x = hrow[k];
    const float* wr = &s_w1[k * HD];
#pragma unroll
    for (int j = 0; j < HD; j++) hid[j] += x * wr[j];
  }
  const float4* ap = (const float4*)(agg + (size_t)n * HD);
#pragma unroll
  for (int k4 = 0; k4 < 16; k4++) {
    float4 v = ap[k4];
    float xs[4] = {v.x, v.y, v.z, v.w};
#pragma unroll
    for (int kk = 0; kk < 4; kk++) {
      float x = xs[kk];
      const float* wr = &s_w1[(64 + 4 * k4 + kk) * HD];
#pragma unroll
      for (int j = 0; j < HD; j++) hid[j] += x * wr[j];
    }
  }
#pragma unroll
  for (int j = 0; j < HD; j++) hid[j] = fmaxf(hid[j], 0.f);
  // hu = h + hid·w_nm2 + b_nm2   (into hrow)
#pragma unroll
  for (int j4 = 0; j4 < 16; j4++) {
    float a0 = s_b2[4 * j4], a1 = s_b2[4 * j4 + 1], a2 = s_b2[4 * j4 + 2], a3 = s_b2[4 * j4 + 3];
#pragma unroll
    for (int k = 0; k < HD; k++) {
      float x = hid[k];
      const float* wr = &s_w2[k * HD + 4 * j4];
      a0 += x * wr[0]; a1 += x * wr[1]; a2 += x * wr[2]; a3 += x * wr[3];
    }
    hrow[4 * j4] += a0; hrow[4 * j4 + 1] += a1; hrow[4 * j4 + 2] += a2; hrow[4 * j4 + 3] += a3;
  }
  // decoder hidden (weights via uniform global reads)
#pragma unroll
  for (int j4 = 0; j4 < 16; j4++) {
    float a0 = b_dec1[4 * j4], a1 = b_dec1[4 * j4 + 1], a2 = b_dec1[4 * j4 + 2], a3 = b_dec1[4 * j4 + 3];
#pragma unroll
    for (int k = 0; k < HD; k++) {
      float x = hrow[k];
      const float* wr = &w_dec1[k * HD + 4 * j4];
      a0 += x * wr[0]; a1 += x * wr[1]; a2 += x * wr[2]; a3 += x * wr[3];
    }
    hid[4 * j4] = fmaxf(a0, 0.f); hid[4 * j4 + 1] = fmaxf(a1, 0.f);
    hid[4 * j4 + 2] = fmaxf(a2, 0.f); hid[4 * j4 + 3] = fmaxf(a3, 0.f);
  }
  float o0 = b_dec2[0], o1 = b_dec2[1], o2 = b_dec2[2];
#pragma unroll
  for (int k = 0; k < HD; k++) {
    float x = hid[k];
    o0 += x * w_dec2[k * 3 + 0]; o1 += x * w_dec2[k * 3 + 1]; o2 += x * w_dec2[k * 3 + 2];
  }
  accv[n * 3 + 0] = o0 * astd[0] + amean[0];
  accv[n * 3 + 1] = o1 * astd[1] + amean[1];
  accv[n * 3 + 2] = o2 * astd[2] + amean[2];
}

// ---------------- RK4 elementwise ----------------
__global__ __launch_bounds__(256) void k_stage(const float* __restrict__ tspan, int s, float c,
    const float* __restrict__ V0, const float* __restrict__ A, float* __restrict__ VS) {
  int i = blockIdx.x * 256 + threadIdx.x;
  if (i >= NN * 3) return;
  float dt = tspan[s + 1] - tspan[s];
  VS[i] = V0[i] + c * dt * A[i];
}

__global__ __launch_bounds__(256) void k_combine(const float* __restrict__ tspan, int s,
    const float* __restrict__ V0, const float* __restrict__ VS1, const float* __restrict__ VS2,
    const float* __restrict__ VS3, const float* __restrict__ A1, const float* __restrict__ A2,
    const float* __restrict__ A3, const float* __restrict__ A4,
    const float* __restrict__ pos_prev, float* __restrict__ pos_next, float* __restrict__ vel_next) {
  int i = blockIdx.x * 256 + threadIdx.x;
  if (i >= NN * 3) return;
  float dt = tspan[s + 1] - tspan[s];
  float sixth = dt / 6.f;
  vel_next[i] = V0[i] + sixth * (A1[i] + 2.f * A2[i] + 2.f * A3[i] + A4[i]);
  pos_next[i] = pos_prev[i] + sixth * (V0[i] + 2.f * VS1[i] + 2.f * VS2[i] + VS3[i]);
}

extern "C" void kernel_launch(void* const* d_in, const int* in_sizes, int n_in,
                              void* d_out, int out_size, void* d_ws, size_t ws_size,
                              hipStream_t stream) {
  (void)in_sizes; (void)n_in; (void)out_size; (void)ws_size;
  const float* world_pos = (const float*)d_in[0];
  const float* velocity  = (const float*)d_in[1];
  const int*   eidx      = (const int*)d_in[2];
  const float* eattr     = (const float*)d_in[3];
  const float* youngs    = (const float*)d_in[4];
  const float* onehot    = (const float*)d_in[5];
  const float* tspan     = (const float*)d_in[7];
  const float* ym        = (const float*)d_in[8];
  const float* ys        = (const float*)d_in[9];
  const float* emean     = (const float*)d_in[10];
  const float* estd      = (const float*)d_in[11];
  const float* vmean     = (const float*)d_in[12];
  const float* vstd      = (const float*)d_in[13];
  const float* amean     = (const float*)d_in[14];
  const float* astd      = (const float*)d_in[15];
  const float* w_ne1 = (const float*)d_in[16]; const float* b_ne1 = (const float*)d_in[17];
  const float* w_ne2 = (const float*)d_in[18]; const float* b_ne2 = (const float*)d_in[19];
  const float* w_ee1 = (const float*)d_in[20]; const float* b_ee1 = (const float*)d_in[21];
  const float* w_ee2 = (const float*)d_in[22]; const float* b_ee2 = (const float*)d_in[23];
  const float* w_em1 = (const float*)d_in[24]; const float* b_em1 = (const float*)d_in[25];
  const float* w_em2 = (const float*)d_in[26]; const float* b_em2 = (const float*)d_in[27];
  const float* w_nm1 = (const float*)d_in[28]; const float* b_nm1 = (const float*)d_in[29];
  const float* w_nm2 = (const float*)d_in[30]; const float* b_nm2 = (const float*)d_in[31];
  const float* w_dec1 = (const float*)d_in[32]; const float* b_dec1 = (const float*)d_in[33];
  const float* w_dec2 = (const float*)d_in[34]; const float* b_dec2 = (const float*)d_in[35];

  char* ws = (char*)d_ws;
  float* h_preT = (float*)ws; ws += (size_t)NN * HD * 4;
  float* e_enc  = (float*)ws; ws += (size_t)NE * HD * 4;
  float* em_pre = (float*)ws; ws += (size_t)NE * HD * 4;
  float* hbuf   = (float*)ws; ws += (size_t)NN * HD * 4;
  float* emsg   = (float*)ws; ws += (size_t)NE * HD * 4;
  float* aggb   = (float*)ws; ws += (size_t)NN * HD * 4;
  float* A0 = (float*)ws; ws += (size_t)NN * 3 * 4;
  float* A1 = (float*)ws; ws += (size_t)NN * 3 * 4;
  float* A2 = (float*)ws; ws += (size_t)NN * 3 * 4;
  float* A3 = (float*)ws; ws += (size_t)NN * 3 * 4;
  float* VS1 = (float*)ws; ws += (size_t)NN * 3 * 4;
  float* VS2 = (float*)ws; ws += (size_t)NN * 3 * 4;
  float* VS3 = (float*)ws; ws += (size_t)NN * 3 * 4;
  int* counts  = (int*)ws; ws += (size_t)NN * 4;
  int* fill    = (int*)ws; ws += (size_t)NN * 4;
  int* row_ptr = (int*)ws; ws += (size_t)(NN + 1) * 4;
  int* slot    = (int*)ws; ws += (size_t)NE * 4;

  float* PO = (float*)d_out;
  float* VO = PO + (size_t)TT * NN * 3;

  // --- once-per-launch precompute ---
  k_init_out<<<(NN * 3 + 255) / 256, 256, 0, stream>>>(world_pos, velocity, PO, VO);
  k_hpre<<<(NN * HD) / 256, 256, 0, stream>>>(youngs, onehot, ym, ys, w_ne1, b_ne1, h_preT);
  k_edge_static<<<NE / 256, 256, 0, stream>>>(eattr, emean, estd, w_ee1, b_ee1, w_ee2, b_ee2,
                                              w_em1, b_em1, e_enc, em_pre);
  k_zero2<<<(NN + 255) / 256, 256, 0, stream>>>(counts, fill);
  k_count<<<NE / 256, 256, 0, stream>>>(eidx, counts);
  k_scan<<<1, 256, 0, stream>>>(counts, row_ptr);
  k_place<<<NE / 256, 256, 0, stream>>>(eidx, row_ptr, fill, slot);

  float* As[4] = {A0, A1, A2, A3};
  float* VSs[3] = {VS1, VS2, VS3};

  for (int s = 0; s < TT - 1; s++) {
    const float* V0 = VO + (size_t)s * NN * 3;
    const float* pos_prev = PO + (size_t)s * NN * 3;
    const float* vin = V0;
    for (int k = 0; k < 4; k++) {
      k_node_enc<<<(NN + 255) / 256, 256, 0, stream>>>(vin, vmean, vstd, w_ne1, h_preT, w_ne2, b_ne2, hbuf);
      k_edge_msg<<<NE / 256, 256, 0, stream>>>(eidx, slot, hbuf, em_pre, e_enc, w_em1, w_em2, b_em2, emsg);
      k_agg<<<(NN + 3) / 4, 256, 0, stream>>>(row_ptr, emsg, aggb);
      k_node_upd<<<(NN + 255) / 256, 256, 0, stream>>>(hbuf, aggb, w_nm1, b_nm1, w_nm2, b_nm2,
                                                       w_dec1, b_dec1, w_dec2, b_dec2, amean, astd, As[k]);
      if (k < 3) {
        float c = (k == 2) ? 1.0f : 0.5f;
        k_stage<<<(NN * 3 + 255) / 256, 256, 0, stream>>>(tspan, s, c, V0, As[k], VSs[k]);
        vin = VSs[k];
      }
    }
    k_combine<<<(NN * 3 + 255) / 256, 256, 0, stream>>>(tspan, s, V0, VS1, VS2, VS3,
                                                        A0, A1, A2, A3, pos_prev,
                                                        PO + (size_t)(s + 1) * NN * 3,
                                                        VO + (size_t)(s + 1) * NN * 3);
  }
}

// Round 2
// 1281.582 us; speedup vs baseline: 1.7721x; 1.7721x over previous
//
#include <hip/hip_runtime.h>
#include <hip/hip_bf16.h>

#define NN 20000
#define NE 160000
#define HD 64
#define TT 3

typedef unsigned short ushortx8 __attribute__((ext_vector_type(8)));
typedef float f32x4 __attribute__((ext_vector_type(4)));
typedef __bf16 bf16x8 __attribute__((ext_vector_type(8)));

__device__ __forceinline__ unsigned short f2bf(float f) {
  unsigned int x = __float_as_uint(f);
  unsigned int r = (x + 0x7fffu + ((x >> 16) & 1u)) >> 16;  // RNE, finite inputs
  return (unsigned short)r;
}
__device__ __forceinline__ float bf2f(unsigned short u) {
  return __uint_as_float(((unsigned int)u) << 16);
}

// ---------------- init: pos_out[0]=world_pos, vel_out[0]=velocity ----------------
__global__ __launch_bounds__(256) void k_init_out(const float* __restrict__ wp,
    const float* __restrict__ vel, float* __restrict__ PO, float* __restrict__ VO) {
  int i = blockIdx.x * 256 + threadIdx.x;
  if (i < NN * 3) { PO[i] = wp[i]; VO[i] = vel[i]; }
}

// ---------------- static node-encoder part ----------------
__global__ __launch_bounds__(256) void k_hpre(const float* __restrict__ youngs,
    const float* __restrict__ onehot, const float* __restrict__ ym, const float* __restrict__ ys,
    const float* __restrict__ w_ne1, const float* __restrict__ b_ne1, float* __restrict__ h_preT) {
  int idx = blockIdx.x * 256 + threadIdx.x;
  if (idx >= NN * HD) return;
  int n = idx % NN, j = idx / NN;
  float a = b_ne1[j];
  float yn = (youngs[n] - ym[0]) / ys[0];
  a += yn * w_ne1[3 * HD + j];
#pragma unroll
  for (int k = 0; k < 9; k++) a += onehot[n * 9 + k] * w_ne1[(4 + k) * HD + j];
  h_preT[(size_t)j * NN + n] = a;
}

// ---------------- static edge encoder (once) -> bf16 ----------------
__global__ __launch_bounds__(256) void k_edge_enc(const float* __restrict__ eattr,
    const float* __restrict__ emean, const float* __restrict__ estd,
    const float* __restrict__ w_ee1, const float* __restrict__ b_ee1,
    const float* __restrict__ w_ee2, const float* __restrict__ b_ee2,
    unsigned short* __restrict__ eenc_bf) {
  __shared__ float s_w1[4 * HD];
  __shared__ float s_w2[HD * HD];
  __shared__ float s_b1[HD], s_b2[HD];
  __shared__ float s_m[4], s_s[4];
  int tid = threadIdx.x;
  for (int i = tid; i < 4 * HD; i += 256) s_w1[i] = w_ee1[i];
  for (int i = tid; i < HD * HD; i += 256) s_w2[i] = w_ee2[i];
  if (tid < HD) { s_b1[tid] = b_ee1[tid]; s_b2[tid] = b_ee2[tid]; }
  if (tid < 4) { s_m[tid] = emean[tid]; s_s[tid] = estd[tid]; }
  __syncthreads();
  int e = blockIdx.x * 256 + tid;
  if (e >= NE) return;
  float x0 = (eattr[e * 4 + 0] - s_m[0]) / s_s[0];
  float x1 = (eattr[e * 4 + 1] - s_m[1]) / s_s[1];
  float x2 = (eattr[e * 4 + 2] - s_m[2]) / s_s[2];
  float x3 = (eattr[e * 4 + 3] - s_m[3]) / s_s[3];
  float hid[HD];
#pragma unroll
  for (int j = 0; j < HD; j++) {
    float a = s_b1[j] + x0 * s_w1[j] + x1 * s_w1[HD + j] + x2 * s_w1[2 * HD + j] + x3 * s_w1[3 * HD + j];
    hid[j] = fmaxf(a, 0.f);
  }
  unsigned short out[HD];
#pragma unroll
  for (int j4 = 0; j4 < 16; j4++) {
    float a0 = s_b2[4 * j4], a1 = s_b2[4 * j4 + 1], a2 = s_b2[4 * j4 + 2], a3 = s_b2[4 * j4 + 3];
#pragma unroll
    for (int k = 0; k < HD; k++) {
      float x = hid[k];
      const float* wr = &s_w2[k * HD + 4 * j4];
      a0 += x * wr[0]; a1 += x * wr[1]; a2 += x * wr[2]; a3 += x * wr[3];
    }
    out[4 * j4] = f2bf(a0); out[4 * j4 + 1] = f2bf(a1);
    out[4 * j4 + 2] = f2bf(a2); out[4 * j4 + 3] = f2bf(a3);
  }
#pragma unroll
  for (int j8 = 0; j8 < 8; j8++) {
    ushortx8 u;
#pragma unroll
    for (int t = 0; t < 8; t++) u[t] = out[j8 * 8 + t];
    ((ushortx8*)(eenc_bf + (size_t)e * HD))[j8] = u;
  }
}

// ---------------- weight prep: transposed bf16 copies of w_em1/w_em2 ----------------
__global__ __launch_bounds__(256) void k_wprep(const float* __restrict__ w_em1,
    const float* __restrict__ w_em2, unsigned short* __restrict__ w1t,
    unsigned short* __restrict__ w2t) {
  int idx = blockIdx.x * 256 + threadIdx.x;
  if (idx < 64 * 192) {
    int j = idx / 192, k = idx % 192;
    w1t[idx] = f2bf(w_em1[k * 64 + j]);
  } else if (idx < 64 * 192 + 64 * 64) {
    int i2 = idx - 64 * 192;
    int j = i2 / 64, k = i2 % 64;
    w2t[i2] = f2bf(w_em2[k * 64 + j]);
  }
}

// ---------------- CSR build ----------------
__global__ __launch_bounds__(256) void k_zero2(int* __restrict__ a, int* __restrict__ b) {
  int i = blockIdx.x * 256 + threadIdx.x;
  if (i < NN) { a[i] = 0; b[i] = 0; }
}

__global__ __launch_bounds__(256) void k_count(const int* __restrict__ eidx, int* __restrict__ counts) {
  int e = blockIdx.x * 256 + threadIdx.x;
  if (e < NE) atomicAdd(&counts[eidx[NE + e]], 1);
}

__global__ __launch_bounds__(256) void k_scan(const int* __restrict__ counts, int* __restrict__ row_ptr) {
  __shared__ int part[256];
  int tid = threadIdx.x;
  const int per = (NN + 255) / 256;
  int base = tid * per;
  int s = 0;
  for (int i = 0; i < per; i++) { int idx = base + i; if (idx < NN) s += counts[idx]; }
  part[tid] = s;
  __syncthreads();
  if (tid == 0) {
    int run = 0;
    for (int i = 0; i < 256; i++) { int v = part[i]; part[i] = run; run += v; }
  }
  __syncthreads();
  int run = part[tid];
  for (int i = 0; i < per; i++) {
    int idx = base + i;
    if (idx < NN) { row_ptr[idx] = run; run += counts[idx]; }
  }
  if (tid == 255) row_ptr[NN] = run;
}

__global__ __launch_bounds__(256) void k_place(const int* __restrict__ eidx,
    const int* __restrict__ row_ptr, int* __restrict__ fill, int* __restrict__ slot) {
  int e = blockIdx.x * 256 + threadIdx.x;
  if (e >= NE) return;
  int d = eidx[NE + e];
  int f = atomicAdd(&fill[d], 1);
  slot[e] = row_ptr[d] + f;
}

// ---------------- per-deriv: node encoder (fp32 compute, fp32 + bf16 out) ----------------
__global__ __launch_bounds__(256) void k_node_enc(const float* __restrict__ vel,
    const float* __restrict__ vmean, const float* __restrict__ vstd,
    const float* __restrict__ w_ne1, const float* __restrict__ h_preT,
    const float* __restrict__ w_ne2, const float* __restrict__ b_ne2,
    float* __restrict__ h, unsigned short* __restrict__ h_bf) {
  __shared__ float s_w1[3 * HD];
  __shared__ float s_w2[HD * HD];
  __shared__ float s_b2[HD];
  __shared__ float s_vm[3], s_vs[3];
  int tid = threadIdx.x;
  for (int i = tid; i < 3 * HD; i += 256) s_w1[i] = w_ne1[i];
  for (int i = tid; i < HD * HD; i += 256) s_w2[i] = w_ne2[i];
  if (tid < HD) s_b2[tid] = b_ne2[tid];
  if (tid < 3) { s_vm[tid] = vmean[tid]; s_vs[tid] = vstd[tid]; }
  __syncthreads();
  int n = blockIdx.x * 256 + tid;
  if (n >= NN) return;
  float v0 = (vel[n * 3 + 0] - s_vm[0]) / s_vs[0];
  float v1 = (vel[n * 3 + 1] - s_vm[1]) / s_vs[1];
  float v2 = (vel[n * 3 + 2] - s_vm[2]) / s_vs[2];
  float hid[HD];
#pragma unroll
  for (int j = 0; j < HD; j++) {
    float a = h_preT[(size_t)j * NN + n] + v0 * s_w1[j] + v1 * s_w1[HD + j] + v2 * s_w1[2 * HD + j];
    hid[j] = fmaxf(a, 0.f);
  }
  float out[HD];
#pragma unroll
  for (int j4 = 0; j4 < 16; j4++) {
    float a0 = s_b2[4 * j4], a1 = s_b2[4 * j4 + 1], a2 = s_b2[4 * j4 + 2], a3 = s_b2[4 * j4 + 3];
#pragma unroll
    for (int k = 0; k < HD; k++) {
      float x = hid[k];
      const float* wr = &s_w2[k * HD + 4 * j4];
      a0 += x * wr[0]; a1 += x * wr[1]; a2 += x * wr[2]; a3 += x * wr[3];
    }
    out[4 * j4] = a0; out[4 * j4 + 1] = a1; out[4 * j4 + 2] = a2; out[4 * j4 + 3] = a3;
    float4 o = {a0, a1, a2, a3};
    ((float4*)(h + (size_t)n * HD))[j4] = o;
  }
#pragma unroll
  for (int j8 = 0; j8 < 8; j8++) {
    ushortx8 u;
#pragma unroll
    for (int t = 0; t < 8; t++) u[t] = f2bf(out[j8 * 8 + t]);
    ((ushortx8*)(h_bf + (size_t)n * HD))[j8] = u;
  }
}

// ---------------- per-deriv: edge message MLP via MFMA (hot kernel) ----------------
// Block: 256 thr = 4 waves, 64 edges. Wave w: edges w*16..+15 (one 16-row M-tile).
// GEMM1: [64e x 192k] x [192k x 64j], K-order: e_enc(0:64) | h_src(64:128) | h_dst(128:192)
// GEMM2: [64e x 64k] x [64k x 64j], residual e_enc folded into C-init.
__global__ __launch_bounds__(256) void k_edge_mfma(
    const int* __restrict__ eidx, const int* __restrict__ slot,
    const unsigned short* __restrict__ h_bf, const unsigned short* __restrict__ eenc_bf,
    const unsigned short* __restrict__ w1t, const unsigned short* __restrict__ w2t,
    const float* __restrict__ b_em1, const float* __restrict__ b_em2,
    unsigned short* __restrict__ emsg) {
  __shared__ __align__(16) char s_w1[64 * 384];   // W1t[j][k] bf16, XOR-swizzled
  __shared__ __align__(16) char s_w2[64 * 128];   // W2t[j][k]
  __shared__ __align__(16) char s_ee[64 * 128];   // e_enc tile [e_loc][c]
  __shared__ __align__(16) char s_hid[64 * 128];  // hid tile (wave-private rows)
  __shared__ float s_b1[64], s_b2[64];
  int tid = threadIdx.x;
  int e0b = blockIdx.x * 64;

  int lane = tid & 63;
  int wv = tid >> 6;
  int l15 = lane & 15;
  int lq = lane >> 4;
  int csub = lq * 8;

  int erow_loc = wv * 16 + l15;
  int eg = e0b + erow_loc;
  int sidx = eidx[eg];
  int didx = eidx[NE + eg];
  int sl = slot[e0b + erow_loc];

  // prefetch global A fragments (h gathers) before the barrier
  const ushortx8* hs = (const ushortx8*)(h_bf + (size_t)sidx * HD);
  const ushortx8* hd = (const ushortx8*)(h_bf + (size_t)didx * HD);
  ushortx8 a2 = hs[lq];
  ushortx8 a3 = hs[4 + lq];
  ushortx8 a4 = hd[lq];
  ushortx8 a5 = hd[4 + lq];

  // stage weights + e_enc tile into LDS (swizzle: byte ^= (row&7)<<4 within row)
  for (int c = tid; c < 1536; c += 256) {
    ushortx8 v = ((const ushortx8*)w1t)[c];
    int j = c / 24, w = (c % 24) * 16;
    *(ushortx8*)(s_w1 + j * 384 + (w ^ ((j & 7) << 4))) = v;
  }
  for (int c = tid; c < 512; c += 256) {
    ushortx8 v = ((const ushortx8*)w2t)[c];
    int j = c >> 3, w = (c & 7) * 16;
    *(ushortx8*)(s_w2 + j * 128 + (w ^ ((j & 7) << 4))) = v;
  }
  for (int c = tid; c < 512; c += 256) {
    ushortx8 v = ((const ushortx8*)(eenc_bf + (size_t)e0b * HD))[c];
    int r = c >> 3, w = (c & 7) * 16;
    *(ushortx8*)(s_ee + r * 128 + (w ^ ((r & 7) << 4))) = v;
  }
  if (tid < 64) { s_b1[tid] = b_em1[tid]; s_b2[tid] = b_em2[tid]; }
  __syncthreads();

  int rsw = (erow_loc & 7) << 4;
  ushortx8 a0 = *(const ushortx8*)(s_ee + erow_loc * 128 + ((csub * 2) ^ rsw));
  ushortx8 a1 = *(const ushortx8*)(s_ee + erow_loc * 128 + ((64 + csub * 2) ^ rsw));

  f32x4 acc[4];
#pragma unroll
  for (int n = 0; n < 4; n++) {
    float bv = s_b1[n * 16 + l15];
#pragma unroll
    for (int i = 0; i < 4; i++) acc[n][i] = bv;
  }
  ushortx8 af[6] = {a0, a1, a2, a3, a4, a5};
#pragma unroll
  for (int kk = 0; kk < 6; kk++) {
    bf16x8 av = __builtin_bit_cast(bf16x8, af[kk]);
#pragma unroll
    for (int n = 0; n < 4; n++) {
      int j = n * 16 + l15;
      ushortx8 bu = *(const ushortx8*)(s_w1 + j * 384 + (((kk * 32 + csub) * 2) ^ ((j & 7) << 4)));
      acc[n] = __builtin_amdgcn_mfma_f32_16x16x32_bf16(av, __builtin_bit_cast(bf16x8, bu), acc[n], 0, 0, 0);
    }
  }
  // relu -> bf16 -> wave-private LDS hid tile (D layout: row=(lq*4+i), col=n*16+l15)
#pragma unroll
  for (int n = 0; n < 4; n++) {
#pragma unroll
    for (int i = 0; i < 4; i++) {
      int r = wv * 16 + lq * 4 + i;
      int col = n * 16 + l15;
      *(unsigned short*)(s_hid + r * 128 + ((col * 2) ^ ((r & 7) << 4))) = f2bf(fmaxf(acc[n][i], 0.f));
    }
  }
  // layer 2: C-init = e_enc residual + b2
  f32x4 acc2[4];
#pragma unroll
  for (int n = 0; n < 4; n++) {
    float bv = s_b2[n * 16 + l15];
#pragma unroll
    for (int i = 0; i < 4; i++) {
      int r = wv * 16 + lq * 4 + i;
      int col = n * 16 + l15;
      unsigned short ev = *(const unsigned short*)(s_ee + r * 128 + ((col * 2) ^ ((r & 7) << 4)));
      acc2[n][i] = bv + bf2f(ev);
    }
  }
#pragma unroll
  for (int kk = 0; kk < 2; kk++) {
    ushortx8 au = *(const ushortx8*)(s_hid + erow_loc * 128 + (((kk * 32 + csub) * 2) ^ rsw));
    bf16x8 av = __builtin_bit_cast(bf16x8, au);
#pragma unroll
    for (int n = 0; n < 4; n++) {
      int j = n * 16 + l15;
      ushortx8 bu = *(const ushortx8*)(s_w2 + j * 128 + (((kk * 32 + csub) * 2) ^ ((j & 7) << 4)));
      acc2[n] = __builtin_amdgcn_mfma_f32_16x16x32_bf16(av, __builtin_bit_cast(bf16x8, bu), acc2[n], 0, 0, 0);
    }
  }
  // out -> bf16 via LDS (reuse s_hid, wave-private), then coalesced scatter to emsg[slot]
#pragma unroll
  for (int n = 0; n < 4; n++) {
#pragma unroll
    for (int i = 0; i < 4; i++) {
      int r = wv * 16 + lq * 4 + i;
      int col = n * 16 + l15;
      *(unsigned short*)(s_hid + r * 128 + ((col * 2) ^ ((r & 7) << 4))) = f2bf(acc2[n][i]);
    }
  }
  ushortx8 q0 = *(const ushortx8*)(s_hid + erow_loc * 128 + ((lq * 32) ^ rsw));
  ushortx8 q1 = *(const ushortx8*)(s_hid + erow_loc * 128 + ((lq * 32 + 16) ^ rsw));
  ushortx8* op = (ushortx8*)(emsg + (size_t)sl * HD);
  op[lq * 2] = q0;
  op[lq * 2 + 1] = q1;
}

// ---------------- per-deriv: aggregation (wave per node, lane per channel, bf16 in) ----------------
__global__ __launch_bounds__(256) void k_agg(const int* __restrict__ row_ptr,
    const unsigned short* __restrict__ emsg, float* __restrict__ agg) {
  int lane = threadIdx.x & 63;
  int wid = threadIdx.x >> 6;
  int n = blockIdx.x * 4 + wid;
  if (n >= NN) return;
  int b = row_ptr[n], e = row_ptr[n + 1];
  float s = 0.f;
  for (int i = b; i < e; i++) s += bf2f(emsg[(size_t)i * HD + lane]);
  agg[(size_t)n * HD + lane] = s;
}

// ---------------- per-deriv: node update + decoder + fused RK4 stage ----------------
__global__ __launch_bounds__(256) void k_node_upd(const float* __restrict__ h,
    const float* __restrict__ agg,
    const float* __restrict__ w_nm1, const float* __restrict__ b_nm1,
    const float* __restrict__ w_nm2, const float* __restrict__ b_nm2,
    const float* __restrict__ w_dec1, const float* __restrict__ b_dec1,
    const float* __restrict__ w_dec2, const float* __restrict__ b_dec2,
    const float* __restrict__ amean, const float* __restrict__ astd, float* __restrict__ accv,
    const float* __restrict__ tspan, int s, float cstage,
    const float* __restrict__ V0, float* __restrict__ VS) {
  __shared__ float s_w1[128 * HD];
  __shared__ float s_w2[HD * HD];
  __shared__ float s_b1[HD], s_b2[HD];
  int tid = threadIdx.x;
  for (int i = tid; i < 128 * HD; i += 256) s_w1[i] = w_nm1[i];
  for (int i = tid; i < HD * HD; i += 256) s_w2[i] = w_nm2[i];
  if (tid < HD) { s_b1[tid] = b_nm1[tid]; s_b2[tid] = b_nm2[tid]; }
  __syncthreads();
  int n = blockIdx.x * 256 + tid;
  if (n >= NN) return;
  float hrow[HD];
  const float4* hp = (const float4*)(h + (size_t)n * HD);
#pragma unroll
  for (int j4 = 0; j4 < 16; j4++) {
    float4 v = hp[j4];
    hrow[4 * j4] = v.x; hrow[4 * j4 + 1] = v.y; hrow[4 * j4 + 2] = v.z; hrow[4 * j4 + 3] = v.w;
  }
  float hid[HD];
#pragma unroll
  for (int j = 0; j < HD; j++) hid[j] = s_b1[j];
#pragma unroll
  for (int k = 0; k < HD; k++) {
    float x = hrow[k];
    const float* wr = &s_w1[k * HD];
#pragma unroll
    for (int j = 0; j < HD; j++) hid[j] += x * wr[j];
  }
  const float4* ap = (const float4*)(agg + (size_t)n * HD);
#pragma unroll
  for (int k4 = 0; k4 < 16; k4++) {
    float4 v = ap[k4];
    float xs[4] = {v.x, v.y, v.z, v.w};
#pragma unroll
    for (int kk = 0; kk < 4; kk++) {
      float x = xs[kk];
      const float* wr = &s_w1[(64 + 4 * k4 + kk) * HD];
#pragma unroll
      for (int j = 0; j < HD; j++) hid[j] += x * wr[j];
    }
  }
#pragma unroll
  for (int j = 0; j < HD; j++) hid[j] = fmaxf(hid[j], 0.f);
#pragma unroll
  for (int j4 = 0; j4 < 16; j4++) {
    float a0 = s_b2[4 * j4], a1 = s_b2[4 * j4 + 1], a2 = s_b2[4 * j4 + 2], a3 = s_b2[4 * j4 + 3];
#pragma unroll
    for (int k = 0; k < HD; k++) {
      float x = hid[k];
      const float* wr = &s_w2[k * HD + 4 * j4];
      a0 += x * wr[0]; a1 += x * wr[1]; a2 += x * wr[2]; a3 += x * wr[3];
    }
    hrow[4 * j4] += a0; hrow[4 * j4 + 1] += a1; hrow[4 * j4 + 2] += a2; hrow[4 * j4 + 3] += a3;
  }
#pragma unroll
  for (int j4 = 0; j4 < 16; j4++) {
    float a0 = b_dec1[4 * j4], a1 = b_dec1[4 * j4 + 1], a2 = b_dec1[4 * j4 + 2], a3 = b_dec1[4 * j4 + 3];
#pragma unroll
    for (int k = 0; k < HD; k++) {
      float x = hrow[k];
      const float* wr = &w_dec1[k * HD + 4 * j4];
      a0 += x * wr[0]; a1 += x * wr[1]; a2 += x * wr[2]; a3 += x * wr[3];
    }
    hid[4 * j4] = fmaxf(a0, 0.f); hid[4 * j4 + 1] = fmaxf(a1, 0.f);
    hid[4 * j4 + 2] = fmaxf(a2, 0.f); hid[4 * j4 + 3] = fmaxf(a3, 0.f);
  }
  float o0 = b_dec2[0], o1 = b_dec2[1], o2 = b_dec2[2];
#pragma unroll
  for (int k = 0; k < HD; k++) {
    float x = hid[k];
    o0 += x * w_dec2[k * 3 + 0]; o1 += x * w_dec2[k * 3 + 1]; o2 += x * w_dec2[k * 3 + 2];
  }
  o0 = o0 * astd[0] + amean[0];
  o1 = o1 * astd[1] + amean[1];
  o2 = o2 * astd[2] + amean[2];
  accv[n * 3 + 0] = o0; accv[n * 3 + 1] = o1; accv[n * 3 + 2] = o2;
  if (VS) {
    float dt = tspan[s + 1] - tspan[s];
    float c = cstage * dt;
    VS[n * 3 + 0] = V0[n * 3 + 0] + c * o0;
    VS[n * 3 + 1] = V0[n * 3 + 1] + c * o1;
    VS[n * 3 + 2] = V0[n * 3 + 2] + c * o2;
  }
}

// ---------------- RK4 combine ----------------
__global__ __launch_bounds__(256) void k_combine(const float* __restrict__ tspan, int s,
    const float* __restrict__ V0, const float* __restrict__ VS1, const float* __restrict__ VS2,
    const float* __restrict__ VS3, const float* __restrict__ A1, const float* __restrict__ A2,
    const float* __restrict__ A3, const float* __restrict__ A4,
    const float* __restrict__ pos_prev, float* __restrict__ pos_next, float* __restrict__ vel_next) {
  int i = blockIdx.x * 256 + threadIdx.x;
  if (i >= NN * 3) return;
  float dt = tspan[s + 1] - tspan[s];
  float sixth = dt / 6.f;
  vel_next[i] = V0[i] + sixth * (A1[i] + 2.f * A2[i] + 2.f * A3[i] + A4[i]);
  pos_next[i] = pos_prev[i] + sixth * (V0[i] + 2.f * VS1[i] + 2.f * VS2[i] + VS3[i]);
}

extern "C" void kernel_launch(void* const* d_in, const int* in_sizes, int n_in,
                              void* d_out, int out_size, void* d_ws, size_t ws_size,
                              hipStream_t stream) {
  (void)in_sizes; (void)n_in; (void)out_size; (void)ws_size;
  const float* world_pos = (const float*)d_in[0];
  const float* velocity  = (const float*)d_in[1];
  const int*   eidx      = (const int*)d_in[2];
  const float* eattr     = (const float*)d_in[3];
  const float* youngs    = (const float*)d_in[4];
  const float* onehot    = (const float*)d_in[5];
  const float* tspan     = (const float*)d_in[7];
  const float* ym        = (const float*)d_in[8];
  const float* ys        = (const float*)d_in[9];
  const float* emean     = (const float*)d_in[10];
  const float* estd      = (const float*)d_in[11];
  const float* vmean     = (const float*)d_in[12];
  const float* vstd      = (const float*)d_in[13];
  const float* amean     = (const float*)d_in[14];
  const float* astd      = (const float*)d_in[15];
  const float* w_ne1 = (const float*)d_in[16]; const float* b_ne1 = (const float*)d_in[17];
  const float* w_ne2 = (const float*)d_in[18]; const float* b_ne2 = (const float*)d_in[19];
  const float* w_ee1 = (const float*)d_in[20]; const float* b_ee1 = (const float*)d_in[21];
  const float* w_ee2 = (const float*)d_in[22]; const float* b_ee2 = (const float*)d_in[23];
  const float* w_em1 = (const float*)d_in[24]; const float* b_em1 = (const float*)d_in[25];
  const float* w_em2 = (const float*)d_in[26]; const float* b_em2 = (const float*)d_in[27];
  const float* w_nm1 = (const float*)d_in[28]; const float* b_nm1 = (const float*)d_in[29];
  const float* w_nm2 = (const float*)d_in[30]; const float* b_nm2 = (const float*)d_in[31];
  const float* w_dec1 = (const float*)d_in[32]; const float* b_dec1 = (const float*)d_in[33];
  const float* w_dec2 = (const float*)d_in[34]; const float* b_dec2 = (const float*)d_in[35];

  char* ws = (char*)d_ws;
  float* h_preT = (float*)ws; ws += (size_t)NN * HD * 4;
  float* hbuf   = (float*)ws; ws += (size_t)NN * HD * 4;
  float* aggb   = (float*)ws; ws += (size_t)NN * HD * 4;
  unsigned short* eenc_bf = (unsigned short*)ws; ws += (size_t)NE * HD * 2;
  unsigned short* emsg_bf = (unsigned short*)ws; ws += (size_t)NE * HD * 2;
  unsigned short* h_bf    = (unsigned short*)ws; ws += (size_t)NN * HD * 2;
  unsigned short* w1t     = (unsigned short*)ws; ws += (size_t)64 * 192 * 2;
  unsigned short* w2t     = (unsigned short*)ws; ws += (size_t)64 * 64 * 2;
  float* A0 = (float*)ws; ws += (size_t)NN * 3 * 4;
  float* A1 = (float*)ws; ws += (size_t)NN * 3 * 4;
  float* A2 = (float*)ws; ws += (size_t)NN * 3 * 4;
  float* A3 = (float*)ws; ws += (size_t)NN * 3 * 4;
  float* VS1 = (float*)ws; ws += (size_t)NN * 3 * 4;
  float* VS2 = (float*)ws; ws += (size_t)NN * 3 * 4;
  float* VS3 = (float*)ws; ws += (size_t)NN * 3 * 4;
  int* counts  = (int*)ws; ws += (size_t)NN * 4;
  int* fill    = (int*)ws; ws += (size_t)NN * 4;
  int* slot    = (int*)ws; ws += (size_t)NE * 4;
  int* row_ptr = (int*)ws; ws += (size_t)(NN + 1) * 4;

  float* PO = (float*)d_out;
  float* VO = PO + (size_t)TT * NN * 3;

  // --- once-per-launch precompute ---
  k_init_out<<<(NN * 3 + 255) / 256, 256, 0, stream>>>(world_pos, velocity, PO, VO);
  k_hpre<<<(NN * HD) / 256, 256, 0, stream>>>(youngs, onehot, ym, ys, w_ne1, b_ne1, h_preT);
  k_edge_enc<<<NE / 256, 256, 0, stream>>>(eattr, emean, estd, w_ee1, b_ee1, w_ee2, b_ee2, eenc_bf);
  k_wprep<<<64, 256, 0, stream>>>(w_em1, w_em2, w1t, w2t);
  k_zero2<<<(NN + 255) / 256, 256, 0, stream>>>(counts, fill);
  k_count<<<NE / 256, 256, 0, stream>>>(eidx, counts);
  k_scan<<<1, 256, 0, stream>>>(counts, row_ptr);
  k_place<<<NE / 256, 256, 0, stream>>>(eidx, row_ptr, fill, slot);

  float* As[4] = {A0, A1, A2, A3};
  float* VSs[3] = {VS1, VS2, VS3};
  const float cst[3] = {0.5f, 0.5f, 1.0f};

  for (int s = 0; s < TT - 1; s++) {
    const float* V0 = VO + (size_t)s * NN * 3;
    const float* pos_prev = PO + (size_t)s * NN * 3;
    const float* vin = V0;
    for (int k = 0; k < 4; k++) {
      k_node_enc<<<(NN + 255) / 256, 256, 0, stream>>>(vin, vmean, vstd, w_ne1, h_preT, w_ne2, b_ne2,
                                                       hbuf, h_bf);
      k_edge_mfma<<<NE / 64, 256, 0, stream>>>(eidx, slot, h_bf, eenc_bf, w1t, w2t, b_em1, b_em2, emsg_bf);
      k_agg<<<(NN + 3) / 4, 256, 0, stream>>>(row_ptr, emsg_bf, aggb);
      float* VS = (k < 3) ? VSs[k] : (float*)nullptr;
      k_node_upd<<<(NN + 255) / 256, 256, 0, stream>>>(hbuf, aggb, w_nm1, b_nm1, w_nm2, b_nm2,
                                                       w_dec1, b_dec1, w_dec2, b_dec2, amean, astd, As[k],
                                                       tspan, s, (k < 3) ? cst[k] : 0.f, V0, VS);
      if (k < 3) vin = VSs[k];
    }
    k_combine<<<(NN * 3 + 255) / 256, 256, 0, stream>>>(tspan, s, V0, VS1, VS2, VS3,
                                                        A0, A1, A2, A3, pos_prev,
                                                        PO + (size_t)(s + 1) * NN * 3,
                                                        VO + (size_t)(s + 1) * NN * 3);
  }
}

// Round 3
// 878.543 us; speedup vs baseline: 2.5851x; 1.4588x over previous
//
#include <hip/hip_runtime.h>
#include <hip/hip_bf16.h>

#define NN 20000
#define NE 160000
#define HD 64
#define TT 3

typedef unsigned short ushortx8 __attribute__((ext_vector_type(8)));
typedef float f32x4 __attribute__((ext_vector_type(4)));
typedef __bf16 bf16x8 __attribute__((ext_vector_type(8)));

__device__ __forceinline__ unsigned short f2bf(float f) {
  unsigned int x = __float_as_uint(f);
  unsigned int r = (x + 0x7fffu + ((x >> 16) & 1u)) >> 16;  // RNE, finite inputs
  return (unsigned short)r;
}
__device__ __forceinline__ float bf2f(unsigned short u) {
  return __uint_as_float(((unsigned int)u) << 16);
}

// ---------------- init ----------------
__global__ __launch_bounds__(256) void k_init_out(const float* __restrict__ wp,
    const float* __restrict__ vel, float* __restrict__ PO, float* __restrict__ VO) {
  int i = blockIdx.x * 256 + threadIdx.x;
  if (i < NN * 3) { PO[i] = wp[i]; VO[i] = vel[i]; }
}

// ---------------- static node-encoder part (row-major now) ----------------
__global__ __launch_bounds__(256) void k_hpre(const float* __restrict__ youngs,
    const float* __restrict__ onehot, const float* __restrict__ ym, const float* __restrict__ ys,
    const float* __restrict__ w_ne1, const float* __restrict__ b_ne1, float* __restrict__ h_pre) {
  int idx = blockIdx.x * 256 + threadIdx.x;
  if (idx >= NN * HD) return;
  int n = idx >> 6, j = idx & 63;
  float a = b_ne1[j];
  float yn = (youngs[n] - ym[0]) / ys[0];
  a += yn * w_ne1[3 * HD + j];
#pragma unroll
  for (int k = 0; k < 9; k++) a += onehot[n * 9 + k] * w_ne1[(4 + k) * HD + j];
  h_pre[idx] = a;
}

// ---------------- static edge encoder (once) -> bf16 ----------------
__global__ __launch_bounds__(256) void k_edge_enc(const float* __restrict__ eattr,
    const float* __restrict__ emean, const float* __restrict__ estd,
    const float* __restrict__ w_ee1, const float* __restrict__ b_ee1,
    const float* __restrict__ w_ee2, const float* __restrict__ b_ee2,
    unsigned short* __restrict__ eenc_bf) {
  __shared__ float s_w1[4 * HD];
  __shared__ float s_w2[HD * HD];
  __shared__ float s_b1[HD], s_b2[HD];
  __shared__ float s_m[4], s_s[4];
  int tid = threadIdx.x;
  for (int i = tid; i < 4 * HD; i += 256) s_w1[i] = w_ee1[i];
  for (int i = tid; i < HD * HD; i += 256) s_w2[i] = w_ee2[i];
  if (tid < HD) { s_b1[tid] = b_ee1[tid]; s_b2[tid] = b_ee2[tid]; }
  if (tid < 4) { s_m[tid] = emean[tid]; s_s[tid] = estd[tid]; }
  __syncthreads();
  int e = blockIdx.x * 256 + tid;
  if (e >= NE) return;
  float x0 = (eattr[e * 4 + 0] - s_m[0]) / s_s[0];
  float x1 = (eattr[e * 4 + 1] - s_m[1]) / s_s[1];
  float x2 = (eattr[e * 4 + 2] - s_m[2]) / s_s[2];
  float x3 = (eattr[e * 4 + 3] - s_m[3]) / s_s[3];
  float hid[HD];
#pragma unroll
  for (int j = 0; j < HD; j++) {
    float a = s_b1[j] + x0 * s_w1[j] + x1 * s_w1[HD + j] + x2 * s_w1[2 * HD + j] + x3 * s_w1[3 * HD + j];
    hid[j] = fmaxf(a, 0.f);
  }
  unsigned short out[HD];
#pragma unroll
  for (int j4 = 0; j4 < 16; j4++) {
    float a0 = s_b2[4 * j4], a1 = s_b2[4 * j4 + 1], a2 = s_b2[4 * j4 + 2], a3 = s_b2[4 * j4 + 3];
#pragma unroll
    for (int k = 0; k < HD; k++) {
      float x = hid[k];
      const float* wr = &s_w2[k * HD + 4 * j4];
      a0 += x * wr[0]; a1 += x * wr[1]; a2 += x * wr[2]; a3 += x * wr[3];
    }
    out[4 * j4] = f2bf(a0); out[4 * j4 + 1] = f2bf(a1);
    out[4 * j4 + 2] = f2bf(a2); out[4 * j4 + 3] = f2bf(a3);
  }
#pragma unroll
  for (int j8 = 0; j8 < 8; j8++) {
    ushortx8 u;
#pragma unroll
    for (int t = 0; t < 8; t++) u[t] = out[j8 * 8 + t];
    ((ushortx8*)(eenc_bf + (size_t)e * HD))[j8] = u;
  }
}

// ---------------- weight prep: all transposed bf16 weights ----------------
__global__ __launch_bounds__(256) void k_wprep_all(const float* __restrict__ w_em1,
    const float* __restrict__ w_em2, const float* __restrict__ w_nm1,
    const float* __restrict__ w_nm2, const float* __restrict__ w_dec1,
    const float* __restrict__ w_ne2,
    unsigned short* __restrict__ w1t_em, unsigned short* __restrict__ w2t_em,
    unsigned short* __restrict__ wnm1t, unsigned short* __restrict__ wnm2t,
    unsigned short* __restrict__ wdec1t, unsigned short* __restrict__ wne2t) {
  int idx = blockIdx.x * 256 + threadIdx.x;
  if (idx < 12288) { int j = idx / 192, k = idx % 192; w1t_em[idx] = f2bf(w_em1[k * 64 + j]); return; }
  idx -= 12288;
  if (idx < 4096) { int j = idx >> 6, k = idx & 63; w2t_em[idx] = f2bf(w_em2[k * 64 + j]); return; }
  idx -= 4096;
  if (idx < 8192) { int j = idx >> 7, k = idx & 127; wnm1t[idx] = f2bf(w_nm1[k * 64 + j]); return; }
  idx -= 8192;
  if (idx < 4096) { int j = idx >> 6, k = idx & 63; wnm2t[idx] = f2bf(w_nm2[k * 64 + j]); return; }
  idx -= 4096;
  if (idx < 4096) { int j = idx >> 6, k = idx & 63; wdec1t[idx] = f2bf(w_dec1[k * 64 + j]); return; }
  idx -= 4096;
  if (idx < 4096) { int j = idx >> 6, k = idx & 63; wne2t[idx] = f2bf(w_ne2[k * 64 + j]); return; }
}

// ---------------- CSR build ----------------
__global__ __launch_bounds__(256) void k_zero2(int* __restrict__ a, int* __restrict__ b) {
  int i = blockIdx.x * 256 + threadIdx.x;
  if (i < NN) { a[i] = 0; b[i] = 0; }
}

__global__ __launch_bounds__(256) void k_count(const int* __restrict__ eidx, int* __restrict__ counts) {
  int e = blockIdx.x * 256 + threadIdx.x;
  if (e < NE) atomicAdd(&counts[eidx[NE + e]], 1);
}

__global__ __launch_bounds__(256) void k_scan(const int* __restrict__ counts, int* __restrict__ row_ptr) {
  __shared__ int part[256];
  int tid = threadIdx.x;
  const int per = (NN + 255) / 256;
  int base = tid * per;
  int s = 0;
  for (int i = 0; i < per; i++) { int idx = base + i; if (idx < NN) s += counts[idx]; }
  part[tid] = s;
  __syncthreads();
  if (tid == 0) {
    int run = 0;
    for (int i = 0; i < 256; i++) { int v = part[i]; part[i] = run; run += v; }
  }
  __syncthreads();
  int run = part[tid];
  for (int i = 0; i < per; i++) {
    int idx = base + i;
    if (idx < NN) { row_ptr[idx] = run; run += counts[idx]; }
  }
  if (tid == 255) row_ptr[NN] = run;
}

__global__ __launch_bounds__(256) void k_place(const int* __restrict__ eidx,
    const int* __restrict__ row_ptr, int* __restrict__ fill, int* __restrict__ slot) {
  int e = blockIdx.x * 256 + threadIdx.x;
  if (e >= NE) return;
  int d = eidx[NE + e];
  int f = atomicAdd(&fill[d], 1);
  slot[e] = row_ptr[d] + f;
}

// ---------------- per-deriv: node encoder via MFMA ----------------
// 64 nodes/block, 4 waves; layer1 lane=channel, GEMM2 16x16x32 MFMA.
__global__ __launch_bounds__(256) void k_enc_mfma(const float* __restrict__ vel,
    const float* __restrict__ vmean, const float* __restrict__ vstd,
    const float* __restrict__ w_ne1, const float* __restrict__ h_pre,
    const unsigned short* __restrict__ wne2t, const float* __restrict__ b_ne2,
    float* __restrict__ h, unsigned short* __restrict__ h_bf) {
  __shared__ __align__(16) char s_w2[64 * 128];
  __shared__ __align__(16) char s_hid[64 * 128];
  __shared__ float s_w1[3 * 64], s_b2[64], s_vm[3], s_vs[3];
  int tid = threadIdx.x, n0b = blockIdx.x * 64;
  for (int c = tid; c < 512; c += 256) {
    ushortx8 v = ((const ushortx8*)wne2t)[c];
    int j = c >> 3, w = (c & 7) * 16;
    *(ushortx8*)(s_w2 + j * 128 + (w ^ ((j & 7) << 4))) = v;
  }
  if (tid < 192) s_w1[tid] = w_ne1[tid];
  if (tid < 64) s_b2[tid] = b_ne2[tid];
  if (tid < 3) { s_vm[tid] = vmean[tid]; s_vs[tid] = vstd[tid]; }
  __syncthreads();
  int lane = tid & 63, wv = tid >> 6, l15 = lane & 15, lq = lane >> 4, csub = lq * 8;
#pragma unroll 4
  for (int i = 0; i < 16; i++) {
    int rl = wv * 16 + i, node = n0b + rl;
    float hv = 0.f;
    if (node < NN) {
      float v0 = (vel[node * 3 + 0] - s_vm[0]) / s_vs[0];
      float v1 = (vel[node * 3 + 1] - s_vm[1]) / s_vs[1];
      float v2 = (vel[node * 3 + 2] - s_vm[2]) / s_vs[2];
      float a = h_pre[(size_t)node * 64 + lane] + v0 * s_w1[lane] + v1 * s_w1[64 + lane] + v2 * s_w1[128 + lane];
      hv = fmaxf(a, 0.f);
    }
    *(unsigned short*)(s_hid + rl * 128 + ((lane * 2) ^ ((rl & 7) << 4))) = f2bf(hv);
  }
  int row_l = wv * 16 + l15, rsw = (l15 & 7) << 4;
  f32x4 acc[4];
#pragma unroll
  for (int n = 0; n < 4; n++) {
    float bv = s_b2[n * 16 + l15];
#pragma unroll
    for (int i = 0; i < 4; i++) acc[n][i] = bv;
  }
#pragma unroll
  for (int kk = 0; kk < 2; kk++) {
    ushortx8 au = *(const ushortx8*)(s_hid + row_l * 128 + (((kk * 32 + csub) * 2) ^ rsw));
    bf16x8 av = __builtin_bit_cast(bf16x8, au);
#pragma unroll
    for (int n = 0; n < 4; n++) {
      int j = n * 16 + l15;
      ushortx8 bu = *(const ushortx8*)(s_w2 + j * 128 + (((kk * 32 + csub) * 2) ^ ((j & 7) << 4)));
      acc[n] = __builtin_amdgcn_mfma_f32_16x16x32_bf16(av, __builtin_bit_cast(bf16x8, bu), acc[n], 0, 0, 0);
    }
  }
  // fp32 h store + bf16 via LDS
#pragma unroll
  for (int n = 0; n < 4; n++) {
#pragma unroll
    for (int i = 0; i < 4; i++) {
      int r = wv * 16 + lq * 4 + i, rowg = n0b + r, col = n * 16 + l15;
      if (rowg < NN) h[(size_t)rowg * 64 + col] = acc[n][i];
      *(unsigned short*)(s_hid + r * 128 + ((col * 2) ^ ((r & 7) << 4))) = f2bf(acc[n][i]);
    }
  }
  int noderow = n0b + row_l;
  if (noderow < NN) {
    ushortx8 q0 = *(const ushortx8*)(s_hid + row_l * 128 + ((lq * 32) ^ rsw));
    ushortx8 q1 = *(const ushortx8*)(s_hid + row_l * 128 + ((lq * 32 + 16) ^ rsw));
    ushortx8* op = (ushortx8*)(h_bf + (size_t)noderow * 64);
    op[lq * 2] = q0;
    op[lq * 2 + 1] = q1;
  }
}

// ---------------- per-deriv: edge message MLP via MFMA ----------------
__global__ __launch_bounds__(256) void k_edge_mfma(
    const int* __restrict__ eidx, const int* __restrict__ slot,
    const unsigned short* __restrict__ h_bf, const unsigned short* __restrict__ eenc_bf,
    const unsigned short* __restrict__ w1t, const unsigned short* __restrict__ w2t,
    const float* __restrict__ b_em1, const float* __restrict__ b_em2,
    unsigned short* __restrict__ emsg) {
  __shared__ __align__(16) char s_w1[64 * 384];
  __shared__ __align__(16) char s_w2[64 * 128];
  __shared__ __align__(16) char s_ee[64 * 128];
  __shared__ __align__(16) char s_hid[64 * 128];
  __shared__ float s_b1[64], s_b2[64];
  int tid = threadIdx.x;
  int e0b = blockIdx.x * 64;
  int lane = tid & 63, wv = tid >> 6, l15 = lane & 15, lq = lane >> 4, csub = lq * 8;
  int erow_loc = wv * 16 + l15;
  int eg = e0b + erow_loc;
  int sidx = eidx[eg];
  int didx = eidx[NE + eg];
  int sl = slot[eg];
  const ushortx8* hs = (const ushortx8*)(h_bf + (size_t)sidx * HD);
  const ushortx8* hd = (const ushortx8*)(h_bf + (size_t)didx * HD);
  ushortx8 a2 = hs[lq];
  ushortx8 a3 = hs[4 + lq];
  ushortx8 a4 = hd[lq];
  ushortx8 a5 = hd[4 + lq];
  for (int c = tid; c < 1536; c += 256) {
    ushortx8 v = ((const ushortx8*)w1t)[c];
    int j = c / 24, w = (c % 24) * 16;
    *(ushortx8*)(s_w1 + j * 384 + (w ^ ((j & 7) << 4))) = v;
  }
  for (int c = tid; c < 512; c += 256) {
    ushortx8 v = ((const ushortx8*)w2t)[c];
    int j = c >> 3, w = (c & 7) * 16;
    *(ushortx8*)(s_w2 + j * 128 + (w ^ ((j & 7) << 4))) = v;
  }
  for (int c = tid; c < 512; c += 256) {
    ushortx8 v = ((const ushortx8*)(eenc_bf + (size_t)e0b * HD))[c];
    int r = c >> 3, w = (c & 7) * 16;
    *(ushortx8*)(s_ee + r * 128 + (w ^ ((r & 7) << 4))) = v;
  }
  if (tid < 64) { s_b1[tid] = b_em1[tid]; s_b2[tid] = b_em2[tid]; }
  __syncthreads();
  int rsw = (erow_loc & 7) << 4;
  ushortx8 a0 = *(const ushortx8*)(s_ee + erow_loc * 128 + ((csub * 2) ^ rsw));
  ushortx8 a1 = *(const ushortx8*)(s_ee + erow_loc * 128 + ((64 + csub * 2) ^ rsw));
  f32x4 acc[4];
#pragma unroll
  for (int n = 0; n < 4; n++) {
    float bv = s_b1[n * 16 + l15];
#pragma unroll
    for (int i = 0; i < 4; i++) acc[n][i] = bv;
  }
  ushortx8 af[6] = {a0, a1, a2, a3, a4, a5};
#pragma unroll
  for (int kk = 0; kk < 6; kk++) {
    bf16x8 av = __builtin_bit_cast(bf16x8, af[kk]);
#pragma unroll
    for (int n = 0; n < 4; n++) {
      int j = n * 16 + l15;
      ushortx8 bu = *(const ushortx8*)(s_w1 + j * 384 + (((kk * 32 + csub) * 2) ^ ((j & 7) << 4)));
      acc[n] = __builtin_amdgcn_mfma_f32_16x16x32_bf16(av, __builtin_bit_cast(bf16x8, bu), acc[n], 0, 0, 0);
    }
  }
#pragma unroll
  for (int n = 0; n < 4; n++) {
#pragma unroll
    for (int i = 0; i < 4; i++) {
      int r = wv * 16 + lq * 4 + i, col = n * 16 + l15;
      *(unsigned short*)(s_hid + r * 128 + ((col * 2) ^ ((r & 7) << 4))) = f2bf(fmaxf(acc[n][i], 0.f));
    }
  }
  f32x4 acc2[4];
#pragma unroll
  for (int n = 0; n < 4; n++) {
    float bv = s_b2[n * 16 + l15];
#pragma unroll
    for (int i = 0; i < 4; i++) {
      int r = wv * 16 + lq * 4 + i, col = n * 16 + l15;
      unsigned short ev = *(const unsigned short*)(s_ee + r * 128 + ((col * 2) ^ ((r & 7) << 4)));
      acc2[n][i] = bv + bf2f(ev);
    }
  }
#pragma unroll
  for (int kk = 0; kk < 2; kk++) {
    ushortx8 au = *(const ushortx8*)(s_hid + erow_loc * 128 + (((kk * 32 + csub) * 2) ^ rsw));
    bf16x8 av = __builtin_bit_cast(bf16x8, au);
#pragma unroll
    for (int n = 0; n < 4; n++) {
      int j = n * 16 + l15;
      ushortx8 bu = *(const ushortx8*)(s_w2 + j * 128 + (((kk * 32 + csub) * 2) ^ ((j & 7) << 4)));
      acc2[n] = __builtin_amdgcn_mfma_f32_16x16x32_bf16(av, __builtin_bit_cast(bf16x8, bu), acc2[n], 0, 0, 0);
    }
  }
#pragma unroll
  for (int n = 0; n < 4; n++) {
#pragma unroll
    for (int i = 0; i < 4; i++) {
      int r = wv * 16 + lq * 4 + i, col = n * 16 + l15;
      *(unsigned short*)(s_hid + r * 128 + ((col * 2) ^ ((r & 7) << 4))) = f2bf(acc2[n][i]);
    }
  }
  ushortx8 q0 = *(const ushortx8*)(s_hid + erow_loc * 128 + ((lq * 32) ^ rsw));
  ushortx8 q1 = *(const ushortx8*)(s_hid + erow_loc * 128 + ((lq * 32 + 16) ^ rsw));
  ushortx8* op = (ushortx8*)(emsg + (size_t)sl * HD);
  op[lq * 2] = q0;
  op[lq * 2 + 1] = q1;
}

// ---------------- per-deriv: fused agg + node update + decoder + RK4 stage ----------------
// 64 nodes/block, 4 waves. Agg into wave-private swizzled LDS tile, then MFMA chain.
__global__ __launch_bounds__(256) void k_upd_fused(
    const int* __restrict__ row_ptr, const unsigned short* __restrict__ emsg,
    const float* __restrict__ hbuf, const unsigned short* __restrict__ h_bf,
    const unsigned short* __restrict__ wnm1t, const unsigned short* __restrict__ wnm2t,
    const unsigned short* __restrict__ wdec1t,
    const float* __restrict__ b_nm1, const float* __restrict__ b_nm2,
    const float* __restrict__ b_dec1, const float* __restrict__ b_dec2,
    const float* __restrict__ w_dec2,
    const float* __restrict__ amean, const float* __restrict__ astd,
    float* __restrict__ accv, const float* __restrict__ tspan, int s, float cstage,
    const float* __restrict__ V0, float* __restrict__ VS) {
  __shared__ __align__(16) char s_w1[64 * 256];   // 16KB wnm1t swizzled
  __shared__ __align__(16) char s_w2[64 * 128];   // 8KB
  __shared__ __align__(16) char s_wd1[64 * 128];  // 8KB
  __shared__ __align__(16) char s_agg[64 * 128];  // 8KB
  __shared__ __align__(16) char s_hid[64 * 128];  // 8KB
  __shared__ float s_b1[64], s_b2[64], s_bd1[64], s_wd2[192];
  int tid = threadIdx.x, n0b = blockIdx.x * 64;
  for (int c = tid; c < 1024; c += 256) {
    ushortx8 v = ((const ushortx8*)wnm1t)[c];
    int j = c >> 4, w = (c & 15) * 16;
    *(ushortx8*)(s_w1 + j * 256 + (w ^ ((j & 7) << 4))) = v;
  }
  for (int c = tid; c < 512; c += 256) {
    ushortx8 v = ((const ushortx8*)wnm2t)[c];
    int j = c >> 3, w = (c & 7) * 16;
    *(ushortx8*)(s_w2 + j * 128 + (w ^ ((j & 7) << 4))) = v;
  }
  for (int c = tid; c < 512; c += 256) {
    ushortx8 v = ((const ushortx8*)wdec1t)[c];
    int j = c >> 3, w = (c & 7) * 16;
    *(ushortx8*)(s_wd1 + j * 128 + (w ^ ((j & 7) << 4))) = v;
  }
  if (tid < 64) { s_b1[tid] = b_nm1[tid]; s_b2[tid] = b_nm2[tid]; s_bd1[tid] = b_dec1[tid]; }
  if (tid < 192) s_wd2[tid] = w_dec2[tid];

  int lane = tid & 63, wv = tid >> 6, l15 = lane & 15, lq = lane >> 4, csub = lq * 8;

  // phase A: aggregate this wave's 16 nodes (lane = channel), wave-private rows
  for (int i = 0; i < 16; i++) {
    int rl = wv * 16 + i, node = n0b + rl;
    float ssum = 0.f;
    if (node < NN) {
      int b = row_ptr[node], e = row_ptr[node + 1];
      for (int r = b; r < e; r++) ssum += bf2f(emsg[(size_t)r * HD + lane]);
    }
    *(unsigned short*)(s_agg + rl * 128 + ((lane * 2) ^ ((rl & 7) << 4))) = f2bf(ssum);
  }
  __syncthreads();  // weights staged by all

  int row_l = wv * 16 + l15, rsw = (l15 & 7) << 4;
  int noderow = n0b + row_l;
  int ncl = noderow < NN ? noderow : NN - 1;

  // GEMM1: [h | agg] x wnm1
  f32x4 acc[4];
#pragma unroll
  for (int n = 0; n < 4; n++) {
    float bv = s_b1[n * 16 + l15];
#pragma unroll
    for (int i = 0; i < 4; i++) acc[n][i] = bv;
  }
  ushortx8 af[4];
  af[0] = *(const ushortx8*)(h_bf + (size_t)ncl * 64 + csub);
  af[1] = *(const ushortx8*)(h_bf + (size_t)ncl * 64 + 32 + csub);
  af[2] = *(const ushortx8*)(s_agg + row_l * 128 + ((csub * 2) ^ rsw));
  af[3] = *(const ushortx8*)(s_agg + row_l * 128 + (((32 + csub) * 2) ^ rsw));
#pragma unroll
  for (int kk = 0; kk < 4; kk++) {
    bf16x8 av = __builtin_bit_cast(bf16x8, af[kk]);
#pragma unroll
    for (int n = 0; n < 4; n++) {
      int j = n * 16 + l15;
      ushortx8 bu = *(const ushortx8*)(s_w1 + j * 256 + (((kk * 32 + csub) * 2) ^ ((j & 7) << 4)));
      acc[n] = __builtin_amdgcn_mfma_f32_16x16x32_bf16(av, __builtin_bit_cast(bf16x8, bu), acc[n], 0, 0, 0);
    }
  }
#pragma unroll
  for (int n = 0; n < 4; n++) {
#pragma unroll
    for (int i = 0; i < 4; i++) {
      int r = wv * 16 + lq * 4 + i, col = n * 16 + l15;
      *(unsigned short*)(s_hid + r * 128 + ((col * 2) ^ ((r & 7) << 4))) = f2bf(fmaxf(acc[n][i], 0.f));
    }
  }
  // GEMM2: hu = h(resid fp32) + b2 + hid x wnm2
  f32x4 acc2[4];
#pragma unroll
  for (int n = 0; n < 4; n++) {
#pragma unroll
    for (int i = 0; i < 4; i++) {
      int r = wv * 16 + lq * 4 + i, col = n * 16 + l15;
      int rg = n0b + r; int rgc = rg < NN ? rg : NN - 1;
      acc2[n][i] = s_b2[col] + hbuf[(size_t)rgc * 64 + col];
    }
  }
#pragma unroll
  for (int kk = 0; kk < 2; kk++) {
    ushortx8 au = *(const ushortx8*)(s_hid + row_l * 128 + (((kk * 32 + csub) * 2) ^ rsw));
    bf16x8 av = __builtin_bit_cast(bf16x8, au);
#pragma unroll
    for (int n = 0; n < 4; n++) {
      int j = n * 16 + l15;
      ushortx8 bu = *(const ushortx8*)(s_w2 + j * 128 + (((kk * 32 + csub) * 2) ^ ((j & 7) << 4)));
      acc2[n] = __builtin_amdgcn_mfma_f32_16x16x32_bf16(av, __builtin_bit_cast(bf16x8, bu), acc2[n], 0, 0, 0);
    }
  }
#pragma unroll
  for (int n = 0; n < 4; n++) {
#pragma unroll
    for (int i = 0; i < 4; i++) {
      int r = wv * 16 + lq * 4 + i, col = n * 16 + l15;
      *(unsigned short*)(s_hid + r * 128 + ((col * 2) ^ ((r & 7) << 4))) = f2bf(acc2[n][i]);
    }
  }
  // dec1
  f32x4 acc3[4];
#pragma unroll
  for (int n = 0; n < 4; n++) {
    float bv = s_bd1[n * 16 + l15];
#pragma unroll
    for (int i = 0; i < 4; i++) acc3[n][i] = bv;
  }
#pragma unroll
  for (int kk = 0; kk < 2; kk++) {
    ushortx8 au = *(const ushortx8*)(s_hid + row_l * 128 + (((kk * 32 + csub) * 2) ^ rsw));
    bf16x8 av = __builtin_bit_cast(bf16x8, au);
#pragma unroll
    for (int n = 0; n < 4; n++) {
      int j = n * 16 + l15;
      ushortx8 bu = *(const ushortx8*)(s_wd1 + j * 128 + (((kk * 32 + csub) * 2) ^ ((j & 7) << 4)));
      acc3[n] = __builtin_amdgcn_mfma_f32_16x16x32_bf16(av, __builtin_bit_cast(bf16x8, bu), acc3[n], 0, 0, 0);
    }
  }
#pragma unroll
  for (int n = 0; n < 4; n++) {
#pragma unroll
    for (int i = 0; i < 4; i++) {
      int r = wv * 16 + lq * 4 + i, col = n * 16 + l15;
      *(unsigned short*)(s_hid + r * 128 + ((col * 2) ^ ((r & 7) << 4))) = f2bf(fmaxf(acc3[n][i], 0.f));
    }
  }
  // dec2: 4 lane-groups x 16 channels, shuffle-reduce
  ushortx8 u0 = *(const ushortx8*)(s_hid + row_l * 128 + ((lq * 32) ^ rsw));
  ushortx8 u1 = *(const ushortx8*)(s_hid + row_l * 128 + ((lq * 32 + 16) ^ rsw));
  float p[3] = {0.f, 0.f, 0.f};
#pragma unroll
  for (int i = 0; i < 8; i++) {
    float x0 = bf2f(u0[i]), x1 = bf2f(u1[i]);
    int c0 = lq * 16 + i, c1 = lq * 16 + 8 + i;
#pragma unroll
    for (int t = 0; t < 3; t++) {
      p[t] += x0 * s_wd2[c0 * 3 + t] + x1 * s_wd2[c1 * 3 + t];
    }
  }
#pragma unroll
  for (int t = 0; t < 3; t++) {
    p[t] += __shfl_xor(p[t], 16);
    p[t] += __shfl_xor(p[t], 32);
  }
  if (noderow < NN && lq < 2) {
    float dt = tspan[s + 1] - tspan[s];
    float c = cstage * dt;
#pragma unroll
    for (int t = 0; t < 3; t++) {
      float o = (p[t] + b_dec2[t]) * astd[t] + amean[t];
      if (lq == 0) accv[noderow * 3 + t] = o;
      else if (VS) VS[noderow * 3 + t] = V0[noderow * 3 + t] + c * o;
    }
  }
}

// ---------------- RK4 combine ----------------
__global__ __launch_bounds__(256) void k_combine(const float* __restrict__ tspan, int s,
    const float* __restrict__ V0, const float* __restrict__ VS1, const float* __restrict__ VS2,
    const float* __restrict__ VS3, const float* __restrict__ A1, const float* __restrict__ A2,
    const float* __restrict__ A3, const float* __restrict__ A4,
    const float* __restrict__ pos_prev, float* __restrict__ pos_next, float* __restrict__ vel_next) {
  int i = blockIdx.x * 256 + threadIdx.x;
  if (i >= NN * 3) return;
  float dt = tspan[s + 1] - tspan[s];
  float sixth = dt / 6.f;
  vel_next[i] = V0[i] + sixth * (A1[i] + 2.f * A2[i] + 2.f * A3[i] + A4[i]);
  pos_next[i] = pos_prev[i] + sixth * (V0[i] + 2.f * VS1[i] + 2.f * VS2[i] + VS3[i]);
}

extern "C" void kernel_launch(void* const* d_in, const int* in_sizes, int n_in,
                              void* d_out, int out_size, void* d_ws, size_t ws_size,
                              hipStream_t stream) {
  (void)in_sizes; (void)n_in; (void)out_size; (void)ws_size;
  const float* world_pos = (const float*)d_in[0];
  const float* velocity  = (const float*)d_in[1];
  const int*   eidx      = (const int*)d_in[2];
  const float* eattr     = (const float*)d_in[3];
  const float* youngs    = (const float*)d_in[4];
  const float* onehot    = (const float*)d_in[5];
  const float* tspan     = (const float*)d_in[7];
  const float* ym        = (const float*)d_in[8];
  const float* ys        = (const float*)d_in[9];
  const float* emean     = (const float*)d_in[10];
  const float* estd      = (const float*)d_in[11];
  const float* vmean     = (const float*)d_in[12];
  const float* vstd      = (const float*)d_in[13];
  const float* amean     = (const float*)d_in[14];
  const float* astd      = (const float*)d_in[15];
  const float* w_ne1 = (const float*)d_in[16]; const float* b_ne1 = (const float*)d_in[17];
  const float* w_ne2 = (const float*)d_in[18]; const float* b_ne2 = (const float*)d_in[19];
  const float* w_ee1 = (const float*)d_in[20]; const float* b_ee1 = (const float*)d_in[21];
  const float* w_ee2 = (const float*)d_in[22]; const float* b_ee2 = (const float*)d_in[23];
  const float* w_em1 = (const float*)d_in[24]; const float* b_em1 = (const float*)d_in[25];
  const float* w_em2 = (const float*)d_in[26]; const float* b_em2 = (const float*)d_in[27];
  const float* w_nm1 = (const float*)d_in[28]; const float* b_nm1 = (const float*)d_in[29];
  const float* w_nm2 = (const float*)d_in[30]; const float* b_nm2 = (const float*)d_in[31];
  const float* w_dec1 = (const float*)d_in[32]; const float* b_dec1 = (const float*)d_in[33];
  const float* w_dec2 = (const float*)d_in[34]; const float* b_dec2 = (const float*)d_in[35];

  char* ws = (char*)d_ws;
  float* h_pre  = (float*)ws; ws += (size_t)NN * HD * 4;
  float* hbuf   = (float*)ws; ws += (size_t)NN * HD * 4;
  unsigned short* eenc_bf = (unsigned short*)ws; ws += (size_t)NE * HD * 2;
  unsigned short* emsg_bf = (unsigned short*)ws; ws += (size_t)NE * HD * 2;
  unsigned short* h_bf    = (unsigned short*)ws; ws += (size_t)NN * HD * 2;
  unsigned short* w1t_em  = (unsigned short*)ws; ws += (size_t)12288 * 2;
  unsigned short* w2t_em  = (unsigned short*)ws; ws += (size_t)4096 * 2;
  unsigned short* wnm1t   = (unsigned short*)ws; ws += (size_t)8192 * 2;
  unsigned short* wnm2t   = (unsigned short*)ws; ws += (size_t)4096 * 2;
  unsigned short* wdec1t  = (unsigned short*)ws; ws += (size_t)4096 * 2;
  unsigned short* wne2t   = (unsigned short*)ws; ws += (size_t)4096 * 2;
  float* A0 = (float*)ws; ws += (size_t)NN * 3 * 4;
  float* A1 = (float*)ws; ws += (size_t)NN * 3 * 4;
  float* A2 = (float*)ws; ws += (size_t)NN * 3 * 4;
  float* A3 = (float*)ws; ws += (size_t)NN * 3 * 4;
  float* VS1 = (float*)ws; ws += (size_t)NN * 3 * 4;
  float* VS2 = (float*)ws; ws += (size_t)NN * 3 * 4;
  float* VS3 = (float*)ws; ws += (size_t)NN * 3 * 4;
  int* counts  = (int*)ws; ws += (size_t)NN * 4;
  int* fill    = (int*)ws; ws += (size_t)NN * 4;
  int* slot    = (int*)ws; ws += (size_t)NE * 4;
  int* row_ptr = (int*)ws; ws += (size_t)(NN + 1) * 4;

  float* PO = (float*)d_out;
  float* VO = PO + (size_t)TT * NN * 3;

  // --- once-per-launch precompute ---
  k_init_out<<<(NN * 3 + 255) / 256, 256, 0, stream>>>(world_pos, velocity, PO, VO);
  k_hpre<<<(NN * HD) / 256, 256, 0, stream>>>(youngs, onehot, ym, ys, w_ne1, b_ne1, h_pre);
  k_edge_enc<<<NE / 256, 256, 0, stream>>>(eattr, emean, estd, w_ee1, b_ee1, w_ee2, b_ee2, eenc_bf);
  k_wprep_all<<<144, 256, 0, stream>>>(w_em1, w_em2, w_nm1, w_nm2, w_dec1, w_ne2,
                                       w1t_em, w2t_em, wnm1t, wnm2t, wdec1t, wne2t);
  k_zero2<<<(NN + 255) / 256, 256, 0, stream>>>(counts, fill);
  k_count<<<NE / 256, 256, 0, stream>>>(eidx, counts);
  k_scan<<<1, 256, 0, stream>>>(counts, row_ptr);
  k_place<<<NE / 256, 256, 0, stream>>>(eidx, row_ptr, fill, slot);

  float* As[4] = {A0, A1, A2, A3};
  float* VSs[3] = {VS1, VS2, VS3};
  const float cst[3] = {0.5f, 0.5f, 1.0f};
  const int NBLK = (NN + 63) / 64;

  for (int s = 0; s < TT - 1; s++) {
    const float* V0 = VO + (size_t)s * NN * 3;
    const float* pos_prev = PO + (size_t)s * NN * 3;
    const float* vin = V0;
    for (int k = 0; k < 4; k++) {
      k_enc_mfma<<<NBLK, 256, 0, stream>>>(vin, vmean, vstd, w_ne1, h_pre, wne2t, b_ne2, hbuf, h_bf);
      k_edge_mfma<<<NE / 64, 256, 0, stream>>>(eidx, slot, h_bf, eenc_bf, w1t_em, w2t_em,
                                               b_em1, b_em2, emsg_bf);
      float* VS = (k < 3) ? VSs[k] : (float*)nullptr;
      k_upd_fused<<<NBLK, 256, 0, stream>>>(row_ptr, emsg_bf, hbuf, h_bf, wnm1t, wnm2t, wdec1t,
                                            b_nm1, b_nm2, b_dec1, b_dec2, w_dec2, amean, astd,
                                            As[k], tspan, s, (k < 3) ? cst[k] : 0.f, V0, VS);
      if (k < 3) vin = VSs[k];
    }
    k_combine<<<(NN * 3 + 255) / 256, 256, 0, stream>>>(tspan, s, V0, VS1, VS2, VS3,
                                                        A0, A1, A2, A3, pos_prev,
                                                        PO + (size_t)(s + 1) * NN * 3,
                                                        VO + (size_t)(s + 1) * NN * 3);
  }
}

// Round 4
// 587.791 us; speedup vs baseline: 3.8638x; 1.4947x over previous
//
#include <hip/hip_runtime.h>
#include <hip/hip_bf16.h>

#define NN 20000
#define NE 160000
#define HD 64
#define TT 3

typedef unsigned short ushortx8 __attribute__((ext_vector_type(8)));
typedef float f32x4 __attribute__((ext_vector_type(4)));
typedef __bf16 bf16x8 __attribute__((ext_vector_type(8)));

__device__ __forceinline__ unsigned short f2bf(float f) {
  unsigned int x = __float_as_uint(f);
  unsigned int r = (x + 0x7fffu + ((x >> 16) & 1u)) >> 16;  // RNE, finite inputs
  return (unsigned short)r;
}
__device__ __forceinline__ float bf2f(unsigned short u) {
  return __uint_as_float(((unsigned int)u) << 16);
}

// ---------------- init ----------------
__global__ __launch_bounds__(256) void k_init_out(const float* __restrict__ wp,
    const float* __restrict__ vel, float* __restrict__ PO, float* __restrict__ VO) {
  int i = blockIdx.x * 256 + threadIdx.x;
  if (i < NN * 3) { PO[i] = wp[i]; VO[i] = vel[i]; }
}

// ---------------- static node-encoder part (row-major) ----------------
__global__ __launch_bounds__(256) void k_hpre(const float* __restrict__ youngs,
    const float* __restrict__ onehot, const float* __restrict__ ym, const float* __restrict__ ys,
    const float* __restrict__ w_ne1, const float* __restrict__ b_ne1, float* __restrict__ h_pre) {
  int idx = blockIdx.x * 256 + threadIdx.x;
  if (idx >= NN * HD) return;
  int n = idx >> 6, j = idx & 63;
  float a = b_ne1[j];
  float yn = (youngs[n] - ym[0]) / ys[0];
  a += yn * w_ne1[3 * HD + j];
#pragma unroll
  for (int k = 0; k < 9; k++) a += onehot[n * 9 + k] * w_ne1[(4 + k) * HD + j];
  h_pre[idx] = a;
}

// ---------------- static edge encoder (once) -> bf16, PRE-SWIZZLED layout ----------------
__global__ __launch_bounds__(256) void k_edge_enc(const float* __restrict__ eattr,
    const float* __restrict__ emean, const float* __restrict__ estd,
    const float* __restrict__ w_ee1, const float* __restrict__ b_ee1,
    const float* __restrict__ w_ee2, const float* __restrict__ b_ee2,
    char* __restrict__ eenc_sw) {
  __shared__ float s_w1[4 * HD];
  __shared__ float s_w2[HD * HD];
  __shared__ float s_b1[HD], s_b2[HD];
  __shared__ float s_m[4], s_s[4];
  int tid = threadIdx.x;
  for (int i = tid; i < 4 * HD; i += 256) s_w1[i] = w_ee1[i];
  for (int i = tid; i < HD * HD; i += 256) s_w2[i] = w_ee2[i];
  if (tid < HD) { s_b1[tid] = b_ee1[tid]; s_b2[tid] = b_ee2[tid]; }
  if (tid < 4) { s_m[tid] = emean[tid]; s_s[tid] = estd[tid]; }
  __syncthreads();
  int e = blockIdx.x * 256 + tid;
  if (e >= NE) return;
  float x0 = (eattr[e * 4 + 0] - s_m[0]) / s_s[0];
  float x1 = (eattr[e * 4 + 1] - s_m[1]) / s_s[1];
  float x2 = (eattr[e * 4 + 2] - s_m[2]) / s_s[2];
  float x3 = (eattr[e * 4 + 3] - s_m[3]) / s_s[3];
  float hid[HD];
#pragma unroll
  for (int j = 0; j < HD; j++) {
    float a = s_b1[j] + x0 * s_w1[j] + x1 * s_w1[HD + j] + x2 * s_w1[2 * HD + j] + x3 * s_w1[3 * HD + j];
    hid[j] = fmaxf(a, 0.f);
  }
  unsigned short out[HD];
#pragma unroll
  for (int j4 = 0; j4 < 16; j4++) {
    float a0 = s_b2[4 * j4], a1 = s_b2[4 * j4 + 1], a2 = s_b2[4 * j4 + 2], a3 = s_b2[4 * j4 + 3];
#pragma unroll
    for (int k = 0; k < HD; k++) {
      float x = hid[k];
      const float* wr = &s_w2[k * HD + 4 * j4];
      a0 += x * wr[0]; a1 += x * wr[1]; a2 += x * wr[2]; a3 += x * wr[3];
    }
    out[4 * j4] = f2bf(a0); out[4 * j4 + 1] = f2bf(a1);
    out[4 * j4 + 2] = f2bf(a2); out[4 * j4 + 3] = f2bf(a3);
  }
  int esw = (e & 7) << 4;
#pragma unroll
  for (int j8 = 0; j8 < 8; j8++) {
    ushortx8 u;
#pragma unroll
    for (int t = 0; t < 8; t++) u[t] = out[j8 * 8 + t];
    *(ushortx8*)(eenc_sw + (size_t)e * 128 + ((j8 * 16) ^ esw)) = u;
  }
}

// ---------------- weight prep: transposed bf16, PRE-SWIZZLED ----------------
__global__ __launch_bounds__(256) void k_wprep_all(const float* __restrict__ w_em1,
    const float* __restrict__ w_em2, const float* __restrict__ w_nm1,
    const float* __restrict__ w_nm2, const float* __restrict__ w_dec1,
    const float* __restrict__ w_ne2,
    char* __restrict__ w1em, char* __restrict__ w2em, char* __restrict__ wnm1,
    char* __restrict__ wnm2, char* __restrict__ wdec1, char* __restrict__ wne2) {
  int idx = blockIdx.x * 256 + threadIdx.x;
  if (idx < 12288) {  // w_em1 [192][64] -> rows j, K=192
    int j = idx / 192, k = idx % 192;
    *(unsigned short*)(w1em + j * 384 + ((k * 2) ^ ((j & 7) << 4))) = f2bf(w_em1[k * 64 + j]);
    return;
  }
  idx -= 12288;
  if (idx < 4096) {
    int j = idx >> 6, k = idx & 63;
    *(unsigned short*)(w2em + j * 128 + ((k * 2) ^ ((j & 7) << 4))) = f2bf(w_em2[k * 64 + j]);
    return;
  }
  idx -= 4096;
  if (idx < 8192) {  // w_nm1 [128][64] -> rows j, K=128
    int j = idx >> 7, k = idx & 127;
    *(unsigned short*)(wnm1 + j * 256 + ((k * 2) ^ ((j & 7) << 4))) = f2bf(w_nm1[k * 64 + j]);
    return;
  }
  idx -= 8192;
  if (idx < 4096) {
    int j = idx >> 6, k = idx & 63;
    *(unsigned short*)(wnm2 + j * 128 + ((k * 2) ^ ((j & 7) << 4))) = f2bf(w_nm2[k * 64 + j]);
    return;
  }
  idx -= 4096;
  if (idx < 4096) {
    int j = idx >> 6, k = idx & 63;
    *(unsigned short*)(wdec1 + j * 128 + ((k * 2) ^ ((j & 7) << 4))) = f2bf(w_dec1[k * 64 + j]);
    return;
  }
  idx -= 4096;
  if (idx < 4096) {
    int j = idx >> 6, k = idx & 63;
    *(unsigned short*)(wne2 + j * 128 + ((k * 2) ^ ((j & 7) << 4))) = f2bf(w_ne2[k * 64 + j]);
    return;
  }
}

// ---------------- CSR build ----------------
__global__ __launch_bounds__(256) void k_zero2(int* __restrict__ a, int* __restrict__ b) {
  int i = blockIdx.x * 256 + threadIdx.x;
  if (i < NN) { a[i] = 0; b[i] = 0; }
}

__global__ __launch_bounds__(256) void k_count(const int* __restrict__ eidx, int* __restrict__ counts) {
  int e = blockIdx.x * 256 + threadIdx.x;
  if (e < NE) atomicAdd(&counts[eidx[NE + e]], 1);
}

__global__ __launch_bounds__(256) void k_scan(const int* __restrict__ counts, int* __restrict__ row_ptr) {
  __shared__ int part[256];
  int tid = threadIdx.x;
  const int per = (NN + 255) / 256;
  int base = tid * per;
  int s = 0;
  for (int i = 0; i < per; i++) { int idx = base + i; if (idx < NN) s += counts[idx]; }
  part[tid] = s;
  __syncthreads();
  if (tid == 0) {
    int run = 0;
    for (int i = 0; i < 256; i++) { int v = part[i]; part[i] = run; run += v; }
  }
  __syncthreads();
  int run = part[tid];
  for (int i = 0; i < per; i++) {
    int idx = base + i;
    if (idx < NN) { row_ptr[idx] = run; run += counts[idx]; }
  }
  if (tid == 255) row_ptr[NN] = run;
}

__global__ __launch_bounds__(256) void k_place(const int* __restrict__ eidx,
    const int* __restrict__ row_ptr, int* __restrict__ fill, int* __restrict__ slot) {
  int e = blockIdx.x * 256 + threadIdx.x;
  if (e >= NE) return;
  int d = eidx[NE + e];
  int f = atomicAdd(&fill[d], 1);
  slot[e] = row_ptr[d] + f;
}

// ---------------- initial node encoder (t=0 only) ----------------
__global__ __launch_bounds__(256) void k_enc_mfma(const float* __restrict__ vel,
    const float* __restrict__ vmean, const float* __restrict__ vstd,
    const float* __restrict__ w_ne1, const float* __restrict__ h_pre,
    const char* __restrict__ wne2sw, const float* __restrict__ b_ne2,
    float* __restrict__ h, unsigned short* __restrict__ h_bf) {
  __shared__ __align__(16) char s_w2[64 * 128];
  __shared__ __align__(16) char s_hid[64 * 128];
  __shared__ float s_w1[3 * 64], s_b2[64], s_vm[3], s_vs[3];
  int tid = threadIdx.x, n0b = blockIdx.x * 64;
  for (int c = tid; c < 512; c += 256) ((ushortx8*)s_w2)[c] = ((const ushortx8*)wne2sw)[c];
  if (tid < 192) s_w1[tid] = w_ne1[tid];
  if (tid < 64) s_b2[tid] = b_ne2[tid];
  if (tid < 3) { s_vm[tid] = vmean[tid]; s_vs[tid] = vstd[tid]; }
  __syncthreads();
  int lane = tid & 63, wv = tid >> 6, l15 = lane & 15, lq = lane >> 4, csub = lq * 8;
#pragma unroll 4
  for (int i = 0; i < 16; i++) {
    int rl = wv * 16 + i, node = n0b + rl;
    float hv = 0.f;
    if (node < NN) {
      float v0 = (vel[node * 3 + 0] - s_vm[0]) / s_vs[0];
      float v1 = (vel[node * 3 + 1] - s_vm[1]) / s_vs[1];
      float v2 = (vel[node * 3 + 2] - s_vm[2]) / s_vs[2];
      float a = h_pre[(size_t)node * 64 + lane] + v0 * s_w1[lane] + v1 * s_w1[64 + lane] + v2 * s_w1[128 + lane];
      hv = fmaxf(a, 0.f);
    }
    *(unsigned short*)(s_hid + rl * 128 + ((lane * 2) ^ ((rl & 7) << 4))) = f2bf(hv);
  }
  int row_l = wv * 16 + l15, rsw = (l15 & 7) << 4;
  f32x4 acc[4];
#pragma unroll
  for (int n = 0; n < 4; n++) {
    float bv = s_b2[n * 16 + l15];
#pragma unroll
    for (int i = 0; i < 4; i++) acc[n][i] = bv;
  }
#pragma unroll
  for (int kk = 0; kk < 2; kk++) {
    ushortx8 au = *(const ushortx8*)(s_hid + row_l * 128 + (((kk * 32 + csub) * 2) ^ rsw));
    bf16x8 av = __builtin_bit_cast(bf16x8, au);
#pragma unroll
    for (int n = 0; n < 4; n++) {
      int j = n * 16 + l15;
      ushortx8 bu = *(const ushortx8*)(s_w2 + j * 128 + (((kk * 32 + csub) * 2) ^ ((j & 7) << 4)));
      acc[n] = __builtin_amdgcn_mfma_f32_16x16x32_bf16(av, __builtin_bit_cast(bf16x8, bu), acc[n], 0, 0, 0);
    }
  }
#pragma unroll
  for (int n = 0; n < 4; n++) {
#pragma unroll
    for (int i = 0; i < 4; i++) {
      int r = wv * 16 + lq * 4 + i, rowg = n0b + r, col = n * 16 + l15;
      if (rowg < NN) h[(size_t)rowg * 64 + col] = acc[n][i];
      *(unsigned short*)(s_hid + r * 128 + ((col * 2) ^ ((r & 7) << 4))) = f2bf(acc[n][i]);
    }
  }
  int noderow = n0b + row_l;
  if (noderow < NN) {
    ushortx8 q0 = *(const ushortx8*)(s_hid + row_l * 128 + ((lq * 32) ^ rsw));
    ushortx8 q1 = *(const ushortx8*)(s_hid + row_l * 128 + ((lq * 32 + 16) ^ rsw));
    ushortx8* op = (ushortx8*)(h_bf + (size_t)noderow * 64);
    op[lq * 2] = q0;
    op[lq * 2 + 1] = q1;
  }
}

// ---------------- per-deriv: edge message MLP via MFMA ----------------
// 64 edges/block, 4 waves. LDS exactly 40KB -> 4 blocks/CU. ee/hid overlay in s_eh.
__global__ __launch_bounds__(256, 4) void k_edge_mfma(
    const int* __restrict__ eidx, const int* __restrict__ slot,
    const unsigned short* __restrict__ h_bf, const char* __restrict__ eenc_sw,
    const char* __restrict__ w1sw, const char* __restrict__ w2sw,
    const float* __restrict__ b_em1, const float* __restrict__ b_em2,
    unsigned short* __restrict__ emsg) {
  __shared__ __align__(16) char s_w1[64 * 384];  // 24KB
  __shared__ __align__(16) char s_w2[64 * 128];  // 8KB
  __shared__ __align__(16) char s_eh[64 * 128];  // 8KB: ee tile, later hid/out (wave-private rows)
  int tid = threadIdx.x, e0b = blockIdx.x * 64;
  int lane = tid & 63, wv = tid >> 6, l15 = lane & 15, lq = lane >> 4, csub = lq * 8;
  int erow_loc = wv * 16 + l15;
  int eg = e0b + erow_loc;
  int sidx = eidx[eg], didx = eidx[NE + eg], sl = slot[eg];
  const ushortx8* hs = (const ushortx8*)(h_bf + (size_t)sidx * HD);
  const ushortx8* hd = (const ushortx8*)(h_bf + (size_t)didx * HD);
  ushortx8 a2 = hs[lq];
  ushortx8 a3 = hs[4 + lq];
  ushortx8 a4 = hd[lq];
  ushortx8 a5 = hd[4 + lq];
  for (int c = tid; c < 1536; c += 256) ((ushortx8*)s_w1)[c] = ((const ushortx8*)w1sw)[c];
  for (int c = tid; c < 512; c += 256) ((ushortx8*)s_w2)[c] = ((const ushortx8*)w2sw)[c];
  {
    const ushortx8* src = (const ushortx8*)(eenc_sw + (size_t)e0b * 128);
    for (int c = tid; c < 512; c += 256) ((ushortx8*)s_eh)[c] = src[c];
  }
  __syncthreads();
  int rsw = (l15 & 7) << 4;
  ushortx8 a0 = *(const ushortx8*)(s_eh + erow_loc * 128 + ((csub * 2) ^ rsw));
  ushortx8 a1 = *(const ushortx8*)(s_eh + erow_loc * 128 + ((64 + csub * 2) ^ rsw));
  f32x4 acc[4];
#pragma unroll
  for (int n = 0; n < 4; n++) {
    float bv = b_em1[n * 16 + l15];
#pragma unroll
    for (int i = 0; i < 4; i++) acc[n][i] = bv;
  }
  ushortx8 af[6] = {a0, a1, a2, a3, a4, a5};
#pragma unroll
  for (int kk = 0; kk < 6; kk++) {
    bf16x8 av = __builtin_bit_cast(bf16x8, af[kk]);
#pragma unroll
    for (int n = 0; n < 4; n++) {
      int j = n * 16 + l15;
      ushortx8 bu = *(const ushortx8*)(s_w1 + j * 384 + (((kk * 32 + csub) * 2) ^ ((j & 7) << 4)));
      acc[n] = __builtin_amdgcn_mfma_f32_16x16x32_bf16(av, __builtin_bit_cast(bf16x8, bu), acc[n], 0, 0, 0);
    }
  }
  // residual C-init from s_eh (ee) BEFORE overwriting with hid (same-wave rows only)
  f32x4 acc2[4];
#pragma unroll
  for (int n = 0; n < 4; n++) {
    float bv = b_em2[n * 16 + l15];
#pragma unroll
    for (int i = 0; i < 4; i++) {
      int r = wv * 16 + lq * 4 + i, col = n * 16 + l15;
      unsigned short ev = *(const unsigned short*)(s_eh + r * 128 + ((col * 2) ^ ((r & 7) << 4)));
      acc2[n][i] = bv + bf2f(ev);
    }
  }
  // relu(acc) -> hid into s_eh (overwrite own rows)
#pragma unroll
  for (int n = 0; n < 4; n++) {
#pragma unroll
    for (int i = 0; i < 4; i++) {
      int r = wv * 16 + lq * 4 + i, col = n * 16 + l15;
      *(unsigned short*)(s_eh + r * 128 + ((col * 2) ^ ((r & 7) << 4))) = f2bf(fmaxf(acc[n][i], 0.f));
    }
  }
#pragma unroll
  for (int kk = 0; kk < 2; kk++) {
    ushortx8 au = *(const ushortx8*)(s_eh + erow_loc * 128 + (((kk * 32 + csub) * 2) ^ rsw));
    bf16x8 av = __builtin_bit_cast(bf16x8, au);
#pragma unroll
    for (int n = 0; n < 4; n++) {
      int j = n * 16 + l15;
      ushortx8 bu = *(const ushortx8*)(s_w2 + j * 128 + (((kk * 32 + csub) * 2) ^ ((j & 7) << 4)));
      acc2[n] = __builtin_amdgcn_mfma_f32_16x16x32_bf16(av, __builtin_bit_cast(bf16x8, bu), acc2[n], 0, 0, 0);
    }
  }
#pragma unroll
  for (int n = 0; n < 4; n++) {
#pragma unroll
    for (int i = 0; i < 4; i++) {
      int r = wv * 16 + lq * 4 + i, col = n * 16 + l15;
      *(unsigned short*)(s_eh + r * 128 + ((col * 2) ^ ((r & 7) << 4))) = f2bf(acc2[n][i]);
    }
  }
  ushortx8 q0 = *(const ushortx8*)(s_eh + erow_loc * 128 + ((lq * 32) ^ rsw));
  ushortx8 q1 = *(const ushortx8*)(s_eh + erow_loc * 128 + ((lq * 32 + 16) ^ rsw));
  ushortx8* op = (ushortx8*)(emsg + (size_t)sl * HD);
  op[lq * 2] = q0;
  op[lq * 2 + 1] = q1;
}

// ---------------- per-deriv: agg + node MLP + decoder + RK4 accum + NEXT encoder ----------------
__global__ __launch_bounds__(256) void k_upd_enc(
    const int* __restrict__ row_ptr, const unsigned short* __restrict__ emsg,
    float* __restrict__ hbuf, unsigned short* __restrict__ h_bf,
    const char* __restrict__ wnm1sw, const char* __restrict__ wnm2sw,
    const char* __restrict__ wdec1sw, const char* __restrict__ wne2sw,
    const float* __restrict__ b_nm1, const float* __restrict__ b_nm2,
    const float* __restrict__ b_dec1, const float* __restrict__ b_dec2,
    const float* __restrict__ w_dec2, const float* __restrict__ amean, const float* __restrict__ astd,
    const float* __restrict__ w_ne1, const float* __restrict__ h_pre,
    const float* __restrict__ b_ne2, const float* __restrict__ vmean, const float* __restrict__ vstd,
    const float* __restrict__ tspan, int s, int k, int do_enc,
    const float* __restrict__ V0, float* __restrict__ vacc, float* __restrict__ pacc,
    const float* __restrict__ pos_prev, float* __restrict__ pos_next, float* __restrict__ vel_next) {
  __shared__ __align__(16) char s_w1[64 * 256];   // 16KB  wnm1
  __shared__ __align__(16) char s_w2[64 * 128];   // 8KB   wnm2
  __shared__ __align__(16) char s_wd1[64 * 128];  // 8KB   wdec1
  __shared__ __align__(16) char s_w2e[64 * 128];  // 8KB   wne2
  __shared__ __align__(16) char s_agg[64 * 128];  // 8KB
  __shared__ __align__(16) char s_hid[64 * 128];  // 8KB
  __shared__ float s_b1[64], s_b2[64], s_bd1[64], s_be2[64], s_wd2[192], s_w1e[192];
  __shared__ float s_vm[3], s_vs[3];
  int tid = threadIdx.x, n0b = blockIdx.x * 64;
  for (int c = tid; c < 1024; c += 256) ((ushortx8*)s_w1)[c] = ((const ushortx8*)wnm1sw)[c];
  for (int c = tid; c < 512; c += 256) ((ushortx8*)s_w2)[c] = ((const ushortx8*)wnm2sw)[c];
  for (int c = tid; c < 512; c += 256) ((ushortx8*)s_wd1)[c] = ((const ushortx8*)wdec1sw)[c];
  for (int c = tid; c < 512; c += 256) ((ushortx8*)s_w2e)[c] = ((const ushortx8*)wne2sw)[c];
  if (tid < 64) { s_b1[tid] = b_nm1[tid]; s_b2[tid] = b_nm2[tid]; s_bd1[tid] = b_dec1[tid]; s_be2[tid] = b_ne2[tid]; }
  if (tid < 192) { s_wd2[tid] = w_dec2[tid]; s_w1e[tid] = w_ne1[tid]; }
  if (tid < 3) { s_vm[tid] = vmean[tid]; s_vs[tid] = vstd[tid]; }

  int lane = tid & 63, wv = tid >> 6, l15 = lane & 15, lq = lane >> 4, csub = lq * 8;
  int row_l = wv * 16 + l15, rsw = (l15 & 7) << 4;
  int noderow = n0b + row_l;
  int ncl = noderow < NN ? noderow : NN - 1;
  // prefetch GEMM1 h fragments (global, own row)
  ushortx8 afh0 = *(const ushortx8*)(h_bf + (size_t)ncl * 64 + csub);
  ushortx8 afh1 = *(const ushortx8*)(h_bf + (size_t)ncl * 64 + 32 + csub);

  // ---- agg: 8 edges x 8 channel-groups in parallel, shfl-xor reduce ----
  int cg = lane & 7;
  for (int i = 0; i < 16; i++) {
    int rl = wv * 16 + i, node = n0b + rl;
    float pf[8] = {0.f, 0.f, 0.f, 0.f, 0.f, 0.f, 0.f, 0.f};
    if (node < NN) {
      int b = row_ptr[node], e = row_ptr[node + 1];
      for (int r = b + (lane >> 3); r < e; r += 8) {
        ushortx8 u = *(const ushortx8*)(emsg + (size_t)r * HD + cg * 8);
#pragma unroll
        for (int j = 0; j < 8; j++) pf[j] += bf2f(u[j]);
      }
    }
#pragma unroll
    for (int j = 0; j < 8; j++) {
      pf[j] += __shfl_xor(pf[j], 8);
      pf[j] += __shfl_xor(pf[j], 16);
      pf[j] += __shfl_xor(pf[j], 32);
    }
    if (lane < 8) {
      ushortx8 u;
#pragma unroll
      for (int j = 0; j < 8; j++) u[j] = f2bf(pf[j]);
      *(ushortx8*)(s_agg + rl * 128 + ((cg * 16) ^ ((rl & 7) << 4))) = u;
    }
  }
  __syncthreads();

  // ---- GEMM1: [h | agg] x wnm1 ----
  f32x4 acc[4];
#pragma unroll
  for (int n = 0; n < 4; n++) {
    float bv = s_b1[n * 16 + l15];
#pragma unroll
    for (int i = 0; i < 4; i++) acc[n][i] = bv;
  }
  ushortx8 af[4];
  af[0] = afh0; af[1] = afh1;
  af[2] = *(const ushortx8*)(s_agg + row_l * 128 + ((csub * 2) ^ rsw));
  af[3] = *(const ushortx8*)(s_agg + row_l * 128 + (((32 + csub) * 2) ^ rsw));
#pragma unroll
  for (int kk = 0; kk < 4; kk++) {
    bf16x8 av = __builtin_bit_cast(bf16x8, af[kk]);
#pragma unroll
    for (int n = 0; n < 4; n++) {
      int j = n * 16 + l15;
      ushortx8 bu = *(const ushortx8*)(s_w1 + j * 256 + (((kk * 32 + csub) * 2) ^ ((j & 7) << 4)));
      acc[n] = __builtin_amdgcn_mfma_f32_16x16x32_bf16(av, __builtin_bit_cast(bf16x8, bu), acc[n], 0, 0, 0);
    }
  }
#pragma unroll
  for (int n = 0; n < 4; n++) {
#pragma unroll
    for (int i = 0; i < 4; i++) {
      int r = wv * 16 + lq * 4 + i, col = n * 16 + l15;
      *(unsigned short*)(s_hid + r * 128 + ((col * 2) ^ ((r & 7) << 4))) = f2bf(fmaxf(acc[n][i], 0.f));
    }
  }
  // ---- GEMM2: hu = h(resid fp32) + b2 + hid x wnm2 ----
  f32x4 acc2[4];
#pragma unroll
  for (int n = 0; n < 4; n++) {
#pragma unroll
    for (int i = 0; i < 4; i++) {
      int r = wv * 16 + lq * 4 + i, col = n * 16 + l15;
      int rg = n0b + r; int rgc = rg < NN ? rg : NN - 1;
      acc2[n][i] = s_b2[col] + hbuf[(size_t)rgc * 64 + col];
    }
  }
#pragma unroll
  for (int kk = 0; kk < 2; kk++) {
    ushortx8 au = *(const ushortx8*)(s_hid + row_l * 128 + (((kk * 32 + csub) * 2) ^ rsw));
    bf16x8 av = __builtin_bit_cast(bf16x8, au);
#pragma unroll
    for (int n = 0; n < 4; n++) {
      int j = n * 16 + l15;
      ushortx8 bu = *(const ushortx8*)(s_w2 + j * 128 + (((kk * 32 + csub) * 2) ^ ((j & 7) << 4)));
      acc2[n] = __builtin_amdgcn_mfma_f32_16x16x32_bf16(av, __builtin_bit_cast(bf16x8, bu), acc2[n], 0, 0, 0);
    }
  }
#pragma unroll
  for (int n = 0; n < 4; n++) {
#pragma unroll
    for (int i = 0; i < 4; i++) {
      int r = wv * 16 + lq * 4 + i, col = n * 16 + l15;
      *(unsigned short*)(s_hid + r * 128 + ((col * 2) ^ ((r & 7) << 4))) = f2bf(acc2[n][i]);
    }
  }
  // ---- dec1 ----
  f32x4 acc3[4];
#pragma unroll
  for (int n = 0; n < 4; n++) {
    float bv = s_bd1[n * 16 + l15];
#pragma unroll
    for (int i = 0; i < 4; i++) acc3[n][i] = bv;
  }
#pragma unroll
  for (int kk = 0; kk < 2; kk++) {
    ushortx8 au = *(const ushortx8*)(s_hid + row_l * 128 + (((kk * 32 + csub) * 2) ^ rsw));
    bf16x8 av = __builtin_bit_cast(bf16x8, au);
#pragma unroll
    for (int n = 0; n < 4; n++) {
      int j = n * 16 + l15;
      ushortx8 bu = *(const ushortx8*)(s_wd1 + j * 128 + (((kk * 32 + csub) * 2) ^ ((j & 7) << 4)));
      acc3[n] = __builtin_amdgcn_mfma_f32_16x16x32_bf16(av, __builtin_bit_cast(bf16x8, bu), acc3[n], 0, 0, 0);
    }
  }
#pragma unroll
  for (int n = 0; n < 4; n++) {
#pragma unroll
    for (int i = 0; i < 4; i++) {
      int r = wv * 16 + lq * 4 + i, col = n * 16 + l15;
      *(unsigned short*)(s_hid + r * 128 + ((col * 2) ^ ((r & 7) << 4))) = f2bf(fmaxf(acc3[n][i], 0.f));
    }
  }
  // ---- dec2: per-lane partial over 16 channels, xor-reduce over lq groups ----
  ushortx8 u0 = *(const ushortx8*)(s_hid + row_l * 128 + ((lq * 32) ^ rsw));
  ushortx8 u1 = *(const ushortx8*)(s_hid + row_l * 128 + ((lq * 32 + 16) ^ rsw));
  float p[3] = {0.f, 0.f, 0.f};
#pragma unroll
  for (int i = 0; i < 8; i++) {
    float x0 = bf2f(u0[i]), x1 = bf2f(u1[i]);
    int c0 = lq * 16 + i, c1 = lq * 16 + 8 + i;
#pragma unroll
    for (int t = 0; t < 3; t++) p[t] += x0 * s_wd2[c0 * 3 + t] + x1 * s_wd2[c1 * 3 + t];
  }
#pragma unroll
  for (int t = 0; t < 3; t++) {
    p[t] += __shfl_xor(p[t], 16);
    p[t] += __shfl_xor(p[t], 32);
  }
  // ---- RK4 bookkeeping ----
  float dt = tspan[s + 1] - tspan[s];
  float o[3];
#pragma unroll
  for (int t = 0; t < 3; t++) o[t] = (p[t] + b_dec2[t]) * astd[t] + amean[t];
  const float ck = (k == 2) ? 1.0f : 0.5f;
  float vs[3] = {0.f, 0.f, 0.f};
  if (noderow < NN) {
    if (lq == 0) {
#pragma unroll
      for (int t = 0; t < 3; t++) {
        float v0v = V0[noderow * 3 + t];
        float wk = (k == 0 || k == 3) ? 1.f : 2.f;
        float va = (k == 0) ? o[t] : vacc[noderow * 3 + t] + wk * o[t];
        if (k < 3) {
          vacc[noderow * 3 + t] = va;
          vs[t] = v0v + ck * dt * o[t];
        } else {
          float vn = v0v + (dt / 6.f) * va;
          vel_next[noderow * 3 + t] = vn;
          vs[t] = vn;
        }
      }
    } else if (lq == 1) {
#pragma unroll
      for (int t = 0; t < 3; t++) {
        if (k < 3) {
          float v0v = V0[noderow * 3 + t];
          float vst = v0v + ck * dt * o[t];
          float pa;
          if (k == 0) pa = v0v + 2.f * vst;
          else pa = pacc[noderow * 3 + t] + ((k == 1) ? 2.f : 1.f) * vst;
          pacc[noderow * 3 + t] = pa;
        } else {
          pos_next[noderow * 3 + t] = pos_prev[noderow * 3 + t] + (dt / 6.f) * pacc[noderow * 3 + t];
        }
      }
    }
  }
  // ---- fused encoder for next stage (reads vs from lq==0 lanes) ----
  if (do_enc) {
    for (int i = 0; i < 16; i++) {
      int rl = wv * 16 + i, node = n0b + rl;
      float v0s = __shfl(vs[0], i);
      float v1s = __shfl(vs[1], i);
      float v2s = __shfl(vs[2], i);
      float hv = 0.f;
      if (node < NN) {
        float vn0 = (v0s - s_vm[0]) / s_vs[0];
        float vn1 = (v1s - s_vm[1]) / s_vs[1];
        float vn2 = (v2s - s_vm[2]) / s_vs[2];
        float a = h_pre[(size_t)node * 64 + lane] + vn0 * s_w1e[lane] + vn1 * s_w1e[64 + lane] + vn2 * s_w1e[128 + lane];
        hv = fmaxf(a, 0.f);
      }
      *(unsigned short*)(s_hid + rl * 128 + ((lane * 2) ^ ((rl & 7) << 4))) = f2bf(hv);
    }
    f32x4 ae[4];
#pragma unroll
    for (int n = 0; n < 4; n++) {
      float bv = s_be2[n * 16 + l15];
#pragma unroll
      for (int i = 0; i < 4; i++) ae[n][i] = bv;
    }
#pragma unroll
    for (int kk = 0; kk < 2; kk++) {
      ushortx8 au = *(const ushortx8*)(s_hid + row_l * 128 + (((kk * 32 + csub) * 2) ^ rsw));
      bf16x8 av = __builtin_bit_cast(bf16x8, au);
#pragma unroll
      for (int n = 0; n < 4; n++) {
        int j = n * 16 + l15;
        ushortx8 bu = *(const ushortx8*)(s_w2e + j * 128 + (((kk * 32 + csub) * 2) ^ ((j & 7) << 4)));
        ae[n] = __builtin_amdgcn_mfma_f32_16x16x32_bf16(av, __builtin_bit_cast(bf16x8, bu), ae[n], 0, 0, 0);
      }
    }
#pragma unroll
    for (int n = 0; n < 4; n++) {
#pragma unroll
      for (int i = 0; i < 4; i++) {
        int r = wv * 16 + lq * 4 + i, rowg = n0b + r, col = n * 16 + l15;
        if (rowg < NN) hbuf[(size_t)rowg * 64 + col] = ae[n][i];
        *(unsigned short*)(s_hid + r * 128 + ((col * 2) ^ ((r & 7) << 4))) = f2bf(ae[n][i]);
      }
    }
    if (noderow < NN) {
      ushortx8 q0 = *(const ushortx8*)(s_hid + row_l * 128 + ((lq * 32) ^ rsw));
      ushortx8 q1 = *(const ushortx8*)(s_hid + row_l * 128 + ((lq * 32 + 16) ^ rsw));
      ushortx8* op = (ushortx8*)(h_bf + (size_t)noderow * 64);
      op[lq * 2] = q0;
      op[lq * 2 + 1] = q1;
    }
  }
}

extern "C" void kernel_launch(void* const* d_in, const int* in_sizes, int n_in,
                              void* d_out, int out_size, void* d_ws, size_t ws_size,
                              hipStream_t stream) {
  (void)in_sizes; (void)n_in; (void)out_size; (void)ws_size;
  const float* world_pos = (const float*)d_in[0];
  const float* velocity  = (const float*)d_in[1];
  const int*   eidx      = (const int*)d_in[2];
  const float* eattr     = (const float*)d_in[3];
  const float* youngs    = (const float*)d_in[4];
  const float* onehot    = (const float*)d_in[5];
  const float* tspan     = (const float*)d_in[7];
  const float* ym        = (const float*)d_in[8];
  const float* ys        = (const float*)d_in[9];
  const float* emean     = (const float*)d_in[10];
  const float* estd      = (const float*)d_in[11];
  const float* vmean     = (const float*)d_in[12];
  const float* vstd      = (const float*)d_in[13];
  const float* amean     = (const float*)d_in[14];
  const float* astd      = (const float*)d_in[15];
  const float* w_ne1 = (const float*)d_in[16]; const float* b_ne1 = (const float*)d_in[17];
  const float* w_ne2 = (const float*)d_in[18]; const float* b_ne2 = (const float*)d_in[19];
  const float* w_ee1 = (const float*)d_in[20]; const float* b_ee1 = (const float*)d_in[21];
  const float* w_ee2 = (const float*)d_in[22]; const float* b_ee2 = (const float*)d_in[23];
  const float* w_em1 = (const float*)d_in[24]; const float* b_em1 = (const float*)d_in[25];
  const float* w_em2 = (const float*)d_in[26]; const float* b_em2 = (const float*)d_in[27];
  const float* w_nm1 = (const float*)d_in[28]; const float* b_nm1 = (const float*)d_in[29];
  const float* w_nm2 = (const float*)d_in[30]; const float* b_nm2 = (const float*)d_in[31];
  const float* w_dec1 = (const float*)d_in[32]; const float* b_dec1 = (const float*)d_in[33];
  const float* w_dec2 = (const float*)d_in[34]; const float* b_dec2 = (const float*)d_in[35];

  char* ws = (char*)d_ws;
  float* h_pre  = (float*)ws; ws += (size_t)NN * HD * 4;
  float* hbuf   = (float*)ws; ws += (size_t)NN * HD * 4;
  char* eenc_sw = ws; ws += (size_t)NE * 128;
  unsigned short* emsg_bf = (unsigned short*)ws; ws += (size_t)NE * HD * 2;
  unsigned short* h_bf    = (unsigned short*)ws; ws += (size_t)NN * HD * 2;
  char* w1em  = ws; ws += 64 * 384;
  char* w2em  = ws; ws += 64 * 128;
  char* wnm1s = ws; ws += 64 * 256;
  char* wnm2s = ws; ws += 64 * 128;
  char* wdec1s = ws; ws += 64 * 128;
  char* wne2s = ws; ws += 64 * 128;
  float* vacc = (float*)ws; ws += (size_t)NN * 3 * 4;
  float* pacc = (float*)ws; ws += (size_t)NN * 3 * 4;
  int* counts  = (int*)ws; ws += (size_t)NN * 4;
  int* fill    = (int*)ws; ws += (size_t)NN * 4;
  int* slot    = (int*)ws; ws += (size_t)NE * 4;
  int* row_ptr = (int*)ws; ws += (size_t)(NN + 1) * 4;

  float* PO = (float*)d_out;
  float* VO = PO + (size_t)TT * NN * 3;

  // --- once-per-launch precompute ---
  k_init_out<<<(NN * 3 + 255) / 256, 256, 0, stream>>>(world_pos, velocity, PO, VO);
  k_hpre<<<(NN * HD) / 256, 256, 0, stream>>>(youngs, onehot, ym, ys, w_ne1, b_ne1, h_pre);
  k_edge_enc<<<NE / 256, 256, 0, stream>>>(eattr, emean, estd, w_ee1, b_ee1, w_ee2, b_ee2, eenc_sw);
  k_wprep_all<<<144, 256, 0, stream>>>(w_em1, w_em2, w_nm1, w_nm2, w_dec1, w_ne2,
                                       w1em, w2em, wnm1s, wnm2s, wdec1s, wne2s);
  k_zero2<<<(NN + 255) / 256, 256, 0, stream>>>(counts, fill);
  k_count<<<NE / 256, 256, 0, stream>>>(eidx, counts);
  k_scan<<<1, 256, 0, stream>>>(counts, row_ptr);
  k_place<<<NE / 256, 256, 0, stream>>>(eidx, row_ptr, fill, slot);

  const int NBLK = (NN + 63) / 64;
  k_enc_mfma<<<NBLK, 256, 0, stream>>>(velocity, vmean, vstd, w_ne1, h_pre, wne2s, b_ne2, hbuf, h_bf);

  for (int s = 0; s < TT - 1; s++) {
    const float* V0 = VO + (size_t)s * NN * 3;
    const float* pos_prev = PO + (size_t)s * NN * 3;
    float* pos_next = PO + (size_t)(s + 1) * NN * 3;
    float* vel_next = VO + (size_t)(s + 1) * NN * 3;
    for (int k = 0; k < 4; k++) {
      k_edge_mfma<<<NE / 64, 256, 0, stream>>>(eidx, slot, h_bf, eenc_sw, w1em, w2em,
                                               b_em1, b_em2, emsg_bf);
      int do_enc = !(s == TT - 2 && k == 3);
      k_upd_enc<<<NBLK, 256, 0, stream>>>(row_ptr, emsg_bf, hbuf, h_bf,
                                          wnm1s, wnm2s, wdec1s, wne2s,
                                          b_nm1, b_nm2, b_dec1, b_dec2, w_dec2, amean, astd,
                                          w_ne1, h_pre, b_ne2, vmean, vstd,
                                          tspan, s, k, do_enc,
                                          V0, vacc, pacc, pos_prev, pos_next, vel_next);
    }
  }
}

// Round 5
// 521.971 us; speedup vs baseline: 4.3510x; 1.1261x over previous
//
#include <hip/hip_runtime.h>
#include <hip/hip_bf16.h>

#define NN 20000
#define NE 160000
#define HD 64
#define TT 3

typedef unsigned short ushortx8 __attribute__((ext_vector_type(8)));
typedef float f32x4 __attribute__((ext_vector_type(4)));
typedef __bf16 bf16x8 __attribute__((ext_vector_type(8)));

__device__ __forceinline__ unsigned short f2bf(float f) {
  unsigned int x = __float_as_uint(f);
  unsigned int r = (x + 0x7fffu + ((x >> 16) & 1u)) >> 16;  // RNE, finite inputs
  return (unsigned short)r;
}
__device__ __forceinline__ float bf2f(unsigned short u) {
  return __uint_as_float(((unsigned int)u) << 16);
}

// ---------------- init ----------------
__global__ __launch_bounds__(256) void k_init_out(const float* __restrict__ wp,
    const float* __restrict__ vel, float* __restrict__ PO, float* __restrict__ VO) {
  int i = blockIdx.x * 256 + threadIdx.x;
  if (i < NN * 3) { PO[i] = wp[i]; VO[i] = vel[i]; }
}

// ---------------- static node-encoder part (row-major) ----------------
__global__ __launch_bounds__(256) void k_hpre(const float* __restrict__ youngs,
    const float* __restrict__ onehot, const float* __restrict__ ym, const float* __restrict__ ys,
    const float* __restrict__ w_ne1, const float* __restrict__ b_ne1, float* __restrict__ h_pre) {
  int idx = blockIdx.x * 256 + threadIdx.x;
  if (idx >= NN * HD) return;
  int n = idx >> 6, j = idx & 63;
  float a = b_ne1[j];
  float yn = (youngs[n] - ym[0]) / ys[0];
  a += yn * w_ne1[3 * HD + j];
#pragma unroll
  for (int k = 0; k < 9; k++) a += onehot[n * 9 + k] * w_ne1[(4 + k) * HD + j];
  h_pre[idx] = a;
}

// ---------------- static edge encoder via MFMA (once) -> pre-swizzled bf16 ----------------
// 64 edges/block, 4 waves. Layer1: lane=channel (K=4). Layer2: MFMA.
// LDS row swizzle == global eenc swizzle (e==rl mod 8), so rows copy verbatim.
__global__ __launch_bounds__(256) void k_edge_enc_mfma(const float* __restrict__ eattr,
    const float* __restrict__ emean, const float* __restrict__ estd,
    const float* __restrict__ w_ee1, const float* __restrict__ b_ee1,
    const char* __restrict__ wee2sw, const float* __restrict__ b_ee2,
    char* __restrict__ eenc_sw) {
  __shared__ __align__(16) char s_w2[64 * 128];
  __shared__ __align__(16) char s_hid[64 * 128];
  __shared__ float s_w1[4 * 64], s_b1[64], s_b2[64], s_m[4], s_s[4];
  int tid = threadIdx.x, e0b = blockIdx.x * 64;
  for (int c = tid; c < 512; c += 256) ((ushortx8*)s_w2)[c] = ((const ushortx8*)wee2sw)[c];
  if (tid < 256) s_w1[tid] = w_ee1[tid];
  if (tid < 64) { s_b1[tid] = b_ee1[tid]; s_b2[tid] = b_ee2[tid]; }
  if (tid < 4) { s_m[tid] = emean[tid]; s_s[tid] = estd[tid]; }
  __syncthreads();
  int lane = tid & 63, wv = tid >> 6, l15 = lane & 15, lq = lane >> 4, csub = lq * 8;
  int row_l = wv * 16 + l15, rsw = (l15 & 7) << 4;
  int erow = e0b + row_l;
  float4 at = ((const float4*)eattr)[erow];
  float x0 = (at.x - s_m[0]) / s_s[0];
  float x1 = (at.y - s_m[1]) / s_s[1];
  float x2 = (at.z - s_m[2]) / s_s[2];
  float x3 = (at.w - s_m[3]) / s_s[3];
#pragma unroll 4
  for (int i = 0; i < 16; i++) {
    int rl = wv * 16 + i;
    float y0 = __shfl(x0, i), y1 = __shfl(x1, i), y2 = __shfl(x2, i), y3 = __shfl(x3, i);
    float a = s_b1[lane] + y0 * s_w1[lane] + y1 * s_w1[64 + lane] + y2 * s_w1[128 + lane] + y3 * s_w1[192 + lane];
    *(unsigned short*)(s_hid + rl * 128 + ((lane * 2) ^ ((rl & 7) << 4))) = f2bf(fmaxf(a, 0.f));
  }
  f32x4 acc[4];
#pragma unroll
  for (int n = 0; n < 4; n++) {
    float bv = s_b2[n * 16 + l15];
#pragma unroll
    for (int i = 0; i < 4; i++) acc[n][i] = bv;
  }
#pragma unroll
  for (int kk = 0; kk < 2; kk++) {
    ushortx8 au = *(const ushortx8*)(s_hid + row_l * 128 + (((kk * 32 + csub) * 2) ^ rsw));
    bf16x8 av = __builtin_bit_cast(bf16x8, au);
#pragma unroll
    for (int n = 0; n < 4; n++) {
      int j = n * 16 + l15;
      ushortx8 bu = *(const ushortx8*)(s_w2 + j * 128 + (((kk * 32 + csub) * 2) ^ ((j & 7) << 4)));
      acc[n] = __builtin_amdgcn_mfma_f32_16x16x32_bf16(av, __builtin_bit_cast(bf16x8, bu), acc[n], 0, 0, 0);
    }
  }
#pragma unroll
  for (int n = 0; n < 4; n++) {
#pragma unroll
    for (int i = 0; i < 4; i++) {
      int r = wv * 16 + lq * 4 + i, col = n * 16 + l15;
      *(unsigned short*)(s_hid + r * 128 + ((col * 2) ^ ((r & 7) << 4))) = f2bf(acc[n][i]);
    }
  }
  // verbatim swizzled-row copy to global
  ushortx8 q0 = *(const ushortx8*)(s_hid + row_l * 128 + lq * 32);
  ushortx8 q1 = *(const ushortx8*)(s_hid + row_l * 128 + lq * 32 + 16);
  *(ushortx8*)(eenc_sw + (size_t)erow * 128 + lq * 32) = q0;
  *(ushortx8*)(eenc_sw + (size_t)erow * 128 + lq * 32 + 16) = q1;
}

// ---------------- weight prep: transposed bf16, PRE-SWIZZLED ----------------
__global__ __launch_bounds__(256) void k_wprep_all(const float* __restrict__ w_em1,
    const float* __restrict__ w_em2, const float* __restrict__ w_nm1,
    const float* __restrict__ w_nm2, const float* __restrict__ w_dec1,
    const float* __restrict__ w_ne2, const float* __restrict__ w_ee2,
    char* __restrict__ w1em, char* __restrict__ w2em, char* __restrict__ wnm1,
    char* __restrict__ wnm2, char* __restrict__ wdec1, char* __restrict__ wne2,
    char* __restrict__ wee2) {
  int idx = blockIdx.x * 256 + threadIdx.x;
  if (idx < 12288) {  // w_em1 [192][64] -> rows j, K=192
    int j = idx / 192, k = idx % 192;
    *(unsigned short*)(w1em + j * 384 + ((k * 2) ^ ((j & 7) << 4))) = f2bf(w_em1[k * 64 + j]);
    return;
  }
  idx -= 12288;
  if (idx < 4096) {
    int j = idx >> 6, k = idx & 63;
    *(unsigned short*)(w2em + j * 128 + ((k * 2) ^ ((j & 7) << 4))) = f2bf(w_em2[k * 64 + j]);
    return;
  }
  idx -= 4096;
  if (idx < 8192) {  // w_nm1 [128][64] -> rows j, K=128
    int j = idx >> 7, k = idx & 127;
    *(unsigned short*)(wnm1 + j * 256 + ((k * 2) ^ ((j & 7) << 4))) = f2bf(w_nm1[k * 64 + j]);
    return;
  }
  idx -= 8192;
  if (idx < 4096) {
    int j = idx >> 6, k = idx & 63;
    *(unsigned short*)(wnm2 + j * 128 + ((k * 2) ^ ((j & 7) << 4))) = f2bf(w_nm2[k * 64 + j]);
    return;
  }
  idx -= 4096;
  if (idx < 4096) {
    int j = idx >> 6, k = idx & 63;
    *(unsigned short*)(wdec1 + j * 128 + ((k * 2) ^ ((j & 7) << 4))) = f2bf(w_dec1[k * 64 + j]);
    return;
  }
  idx -= 4096;
  if (idx < 4096) {
    int j = idx >> 6, k = idx & 63;
    *(unsigned short*)(wne2 + j * 128 + ((k * 2) ^ ((j & 7) << 4))) = f2bf(w_ne2[k * 64 + j]);
    return;
  }
  idx -= 4096;
  if (idx < 4096) {
    int j = idx >> 6, k = idx & 63;
    *(unsigned short*)(wee2 + j * 128 + ((k * 2) ^ ((j & 7) << 4))) = f2bf(w_ee2[k * 64 + j]);
    return;
  }
}

// ---------------- CSR build ----------------
__global__ __launch_bounds__(256) void k_zero2(int* __restrict__ a, int* __restrict__ b) {
  int i = blockIdx.x * 256 + threadIdx.x;
  if (i < NN) { a[i] = 0; b[i] = 0; }
}

__global__ __launch_bounds__(256) void k_count(const int* __restrict__ eidx, int* __restrict__ counts) {
  int e = blockIdx.x * 256 + threadIdx.x;
  if (e < NE) atomicAdd(&counts[eidx[NE + e]], 1);
}

__global__ __launch_bounds__(256) void k_scan(const int* __restrict__ counts, int* __restrict__ row_ptr) {
  __shared__ int part[256];
  int tid = threadIdx.x;
  const int per = (NN + 255) / 256;
  int base = tid * per;
  int s = 0;
  for (int i = 0; i < per; i++) { int idx = base + i; if (idx < NN) s += counts[idx]; }
  part[tid] = s;
  __syncthreads();
  if (tid == 0) {
    int run = 0;
    for (int i = 0; i < 256; i++) { int v = part[i]; part[i] = run; run += v; }
  }
  __syncthreads();
  int run = part[tid];
  for (int i = 0; i < per; i++) {
    int idx = base + i;
    if (idx < NN) { row_ptr[idx] = run; run += counts[idx]; }
  }
  if (tid == 255) row_ptr[NN] = run;
}

__global__ __launch_bounds__(256) void k_place(const int* __restrict__ eidx,
    const int* __restrict__ row_ptr, int* __restrict__ fill, int* __restrict__ slot) {
  int e = blockIdx.x * 256 + threadIdx.x;
  if (e >= NE) return;
  int d = eidx[NE + e];
  int f = atomicAdd(&fill[d], 1);
  slot[e] = row_ptr[d] + f;
}

// ---------------- initial node encoder (t=0 only) ----------------
__global__ __launch_bounds__(256) void k_enc_mfma(const float* __restrict__ vel,
    const float* __restrict__ vmean, const float* __restrict__ vstd,
    const float* __restrict__ w_ne1, const float* __restrict__ h_pre,
    const char* __restrict__ wne2sw, const float* __restrict__ b_ne2,
    float* __restrict__ h, unsigned short* __restrict__ h_bf) {
  __shared__ __align__(16) char s_w2[64 * 128];
  __shared__ __align__(16) char s_hid[64 * 128];
  __shared__ float s_w1[3 * 64], s_b2[64], s_vm[3], s_vs[3];
  int tid = threadIdx.x, n0b = blockIdx.x * 64;
  for (int c = tid; c < 512; c += 256) ((ushortx8*)s_w2)[c] = ((const ushortx8*)wne2sw)[c];
  if (tid < 192) s_w1[tid] = w_ne1[tid];
  if (tid < 64) s_b2[tid] = b_ne2[tid];
  if (tid < 3) { s_vm[tid] = vmean[tid]; s_vs[tid] = vstd[tid]; }
  __syncthreads();
  int lane = tid & 63, wv = tid >> 6, l15 = lane & 15, lq = lane >> 4, csub = lq * 8;
#pragma unroll 4
  for (int i = 0; i < 16; i++) {
    int rl = wv * 16 + i, node = n0b + rl;
    float hv = 0.f;
    if (node < NN) {
      float v0 = (vel[node * 3 + 0] - s_vm[0]) / s_vs[0];
      float v1 = (vel[node * 3 + 1] - s_vm[1]) / s_vs[1];
      float v2 = (vel[node * 3 + 2] - s_vm[2]) / s_vs[2];
      float a = h_pre[(size_t)node * 64 + lane] + v0 * s_w1[lane] + v1 * s_w1[64 + lane] + v2 * s_w1[128 + lane];
      hv = fmaxf(a, 0.f);
    }
    *(unsigned short*)(s_hid + rl * 128 + ((lane * 2) ^ ((rl & 7) << 4))) = f2bf(hv);
  }
  int row_l = wv * 16 + l15, rsw = (l15 & 7) << 4;
  f32x4 acc[4];
#pragma unroll
  for (int n = 0; n < 4; n++) {
    float bv = s_b2[n * 16 + l15];
#pragma unroll
    for (int i = 0; i < 4; i++) acc[n][i] = bv;
  }
#pragma unroll
  for (int kk = 0; kk < 2; kk++) {
    ushortx8 au = *(const ushortx8*)(s_hid + row_l * 128 + (((kk * 32 + csub) * 2) ^ rsw));
    bf16x8 av = __builtin_bit_cast(bf16x8, au);
#pragma unroll
    for (int n = 0; n < 4; n++) {
      int j = n * 16 + l15;
      ushortx8 bu = *(const ushortx8*)(s_w2 + j * 128 + (((kk * 32 + csub) * 2) ^ ((j & 7) << 4)));
      acc[n] = __builtin_amdgcn_mfma_f32_16x16x32_bf16(av, __builtin_bit_cast(bf16x8, bu), acc[n], 0, 0, 0);
    }
  }
#pragma unroll
  for (int n = 0; n < 4; n++) {
#pragma unroll
    for (int i = 0; i < 4; i++) {
      int r = wv * 16 + lq * 4 + i, rowg = n0b + r, col = n * 16 + l15;
      if (rowg < NN) h[(size_t)rowg * 64 + col] = acc[n][i];
      *(unsigned short*)(s_hid + r * 128 + ((col * 2) ^ ((r & 7) << 4))) = f2bf(acc[n][i]);
    }
  }
  int noderow = n0b + row_l;
  if (noderow < NN) {
    ushortx8 q0 = *(const ushortx8*)(s_hid + row_l * 128 + ((lq * 32) ^ rsw));
    ushortx8 q1 = *(const ushortx8*)(s_hid + row_l * 128 + ((lq * 32 + 16) ^ rsw));
    ushortx8* op = (ushortx8*)(h_bf + (size_t)noderow * 64);
    op[lq * 2] = q0;
    op[lq * 2 + 1] = q1;
  }
}

// ---------------- per-deriv: edge message MLP via MFMA, persistent tile loop ----------------
// grid=1024 (4 blocks/CU at 40KB LDS); weights staged ONCE per block.
#define EDGE_GRID 1024
__global__ __launch_bounds__(256, 4) void k_edge_mfma(
    const int* __restrict__ eidx, const int* __restrict__ slot,
    const unsigned short* __restrict__ h_bf, const char* __restrict__ eenc_sw,
    const char* __restrict__ w1sw, const char* __restrict__ w2sw,
    const float* __restrict__ b_em1, const float* __restrict__ b_em2,
    unsigned short* __restrict__ emsg) {
  __shared__ __align__(16) char s_w1[64 * 384];  // 24KB
  __shared__ __align__(16) char s_w2[64 * 128];  // 8KB
  __shared__ __align__(16) char s_eh[64 * 128];  // 8KB: ee tile, later hid/out (wave-private rows)
  int tid = threadIdx.x;
  int lane = tid & 63, wv = tid >> 6, l15 = lane & 15, lq = lane >> 4, csub = lq * 8;
  int erow_loc = wv * 16 + l15;
  int rsw = (l15 & 7) << 4;
  for (int c = tid; c < 1536; c += 256) ((ushortx8*)s_w1)[c] = ((const ushortx8*)w1sw)[c];
  for (int c = tid; c < 512; c += 256) ((ushortx8*)s_w2)[c] = ((const ushortx8*)w2sw)[c];
  float bv1[4], bv2[4];
#pragma unroll
  for (int n = 0; n < 4; n++) { bv1[n] = b_em1[n * 16 + l15]; bv2[n] = b_em2[n * 16 + l15]; }

  const int NT = NE / 64;
  for (int t = blockIdx.x; t < NT; t += EDGE_GRID) {
    int e0b = t * 64;
    int eg = e0b + erow_loc;
    int sidx = eidx[eg], didx = eidx[NE + eg], sl = slot[eg];
    const ushortx8* hs = (const ushortx8*)(h_bf + (size_t)sidx * HD);
    const ushortx8* hd = (const ushortx8*)(h_bf + (size_t)didx * HD);
    ushortx8 a2 = hs[lq];
    ushortx8 a3 = hs[4 + lq];
    ushortx8 a4 = hd[lq];
    ushortx8 a5 = hd[4 + lq];
    __syncthreads();  // prior tile done with s_eh (and 1st iter: weights visible)
    {
      const ushortx8* src = (const ushortx8*)(eenc_sw + (size_t)e0b * 128);
      for (int c = tid; c < 512; c += 256) ((ushortx8*)s_eh)[c] = src[c];
    }
    __syncthreads();
    ushortx8 a0 = *(const ushortx8*)(s_eh + erow_loc * 128 + ((csub * 2) ^ rsw));
    ushortx8 a1 = *(const ushortx8*)(s_eh + erow_loc * 128 + ((64 + csub * 2) ^ rsw));
    f32x4 acc[4];
#pragma unroll
    for (int n = 0; n < 4; n++) {
#pragma unroll
      for (int i = 0; i < 4; i++) acc[n][i] = bv1[n];
    }
    ushortx8 af[6] = {a0, a1, a2, a3, a4, a5};
#pragma unroll
    for (int kk = 0; kk < 6; kk++) {
      bf16x8 av = __builtin_bit_cast(bf16x8, af[kk]);
#pragma unroll
      for (int n = 0; n < 4; n++) {
        int j = n * 16 + l15;
        ushortx8 bu = *(const ushortx8*)(s_w1 + j * 384 + (((kk * 32 + csub) * 2) ^ ((j & 7) << 4)));
        acc[n] = __builtin_amdgcn_mfma_f32_16x16x32_bf16(av, __builtin_bit_cast(bf16x8, bu), acc[n], 0, 0, 0);
      }
    }
    // residual C-init from s_eh (ee) BEFORE overwriting with hid (own-wave rows only)
    f32x4 acc2[4];
#pragma unroll
    for (int n = 0; n < 4; n++) {
#pragma unroll
      for (int i = 0; i < 4; i++) {
        int r = wv * 16 + lq * 4 + i, col = n * 16 + l15;
        unsigned short ev = *(const unsigned short*)(s_eh + r * 128 + ((col * 2) ^ ((r & 7) << 4)));
        acc2[n][i] = bv2[n] + bf2f(ev);
      }
    }
#pragma unroll
    for (int n = 0; n < 4; n++) {
#pragma unroll
      for (int i = 0; i < 4; i++) {
        int r = wv * 16 + lq * 4 + i, col = n * 16 + l15;
        *(unsigned short*)(s_eh + r * 128 + ((col * 2) ^ ((r & 7) << 4))) = f2bf(fmaxf(acc[n][i], 0.f));
      }
    }
#pragma unroll
    for (int kk = 0; kk < 2; kk++) {
      ushortx8 au = *(const ushortx8*)(s_eh + erow_loc * 128 + (((kk * 32 + csub) * 2) ^ rsw));
      bf16x8 av = __builtin_bit_cast(bf16x8, au);
#pragma unroll
      for (int n = 0; n < 4; n++) {
        int j = n * 16 + l15;
        ushortx8 bu = *(const ushortx8*)(s_w2 + j * 128 + (((kk * 32 + csub) * 2) ^ ((j & 7) << 4)));
        acc2[n] = __builtin_amdgcn_mfma_f32_16x16x32_bf16(av, __builtin_bit_cast(bf16x8, bu), acc2[n], 0, 0, 0);
      }
    }
#pragma unroll
    for (int n = 0; n < 4; n++) {
#pragma unroll
      for (int i = 0; i < 4; i++) {
        int r = wv * 16 + lq * 4 + i, col = n * 16 + l15;
        *(unsigned short*)(s_eh + r * 128 + ((col * 2) ^ ((r & 7) << 4))) = f2bf(acc2[n][i]);
      }
    }
    ushortx8 q0 = *(const ushortx8*)(s_eh + erow_loc * 128 + ((lq * 32) ^ rsw));
    ushortx8 q1 = *(const ushortx8*)(s_eh + erow_loc * 128 + ((lq * 32 + 16) ^ rsw));
    ushortx8* op = (ushortx8*)(emsg + (size_t)sl * HD);
    op[lq * 2] = q0;
    op[lq * 2 + 1] = q1;
  }
}

// ---------------- per-deriv: agg + node MLP + decoder + RK4 accum + NEXT encoder ----------------
__global__ __launch_bounds__(256) void k_upd_enc(
    const int* __restrict__ row_ptr, const unsigned short* __restrict__ emsg,
    float* __restrict__ hbuf, unsigned short* __restrict__ h_bf,
    const char* __restrict__ wnm1sw, const char* __restrict__ wnm2sw,
    const char* __restrict__ wdec1sw, const char* __restrict__ wne2sw,
    const float* __restrict__ b_nm1, const float* __restrict__ b_nm2,
    const float* __restrict__ b_dec1, const float* __restrict__ b_dec2,
    const float* __restrict__ w_dec2, const float* __restrict__ amean, const float* __restrict__ astd,
    const float* __restrict__ w_ne1, const float* __restrict__ h_pre,
    const float* __restrict__ b_ne2, const float* __restrict__ vmean, const float* __restrict__ vstd,
    const float* __restrict__ tspan, int s, int k, int do_enc,
    const float* __restrict__ V0, float* __restrict__ vacc, float* __restrict__ pacc,
    const float* __restrict__ pos_prev, float* __restrict__ pos_next, float* __restrict__ vel_next) {
  __shared__ __align__(16) char s_w1[64 * 256];   // 16KB  wnm1
  __shared__ __align__(16) char s_w2[64 * 128];   // 8KB   wnm2
  __shared__ __align__(16) char s_wd1[64 * 128];  // 8KB   wdec1
  __shared__ __align__(16) char s_w2e[64 * 128];  // 8KB   wne2
  __shared__ __align__(16) char s_agg[64 * 128];  // 8KB
  __shared__ __align__(16) char s_hid[64 * 128];  // 8KB
  __shared__ float s_b1[64], s_b2[64], s_bd1[64], s_be2[64], s_wd2[192], s_w1e[192];
  __shared__ float s_vm[3], s_vs[3];
  int tid = threadIdx.x, n0b = blockIdx.x * 64;
  for (int c = tid; c < 1024; c += 256) ((ushortx8*)s_w1)[c] = ((const ushortx8*)wnm1sw)[c];
  for (int c = tid; c < 512; c += 256) ((ushortx8*)s_w2)[c] = ((const ushortx8*)wnm2sw)[c];
  for (int c = tid; c < 512; c += 256) ((ushortx8*)s_wd1)[c] = ((const ushortx8*)wdec1sw)[c];
  for (int c = tid; c < 512; c += 256) ((ushortx8*)s_w2e)[c] = ((const ushortx8*)wne2sw)[c];
  if (tid < 64) { s_b1[tid] = b_nm1[tid]; s_b2[tid] = b_nm2[tid]; s_bd1[tid] = b_dec1[tid]; s_be2[tid] = b_ne2[tid]; }
  if (tid < 192) { s_wd2[tid] = w_dec2[tid]; s_w1e[tid] = w_ne1[tid]; }
  if (tid < 3) { s_vm[tid] = vmean[tid]; s_vs[tid] = vstd[tid]; }

  int lane = tid & 63, wv = tid >> 6, l15 = lane & 15, lq = lane >> 4, csub = lq * 8;
  int row_l = wv * 16 + l15, rsw = (l15 & 7) << 4;
  int noderow = n0b + row_l;
  int ncl = noderow < NN ? noderow : NN - 1;
  // prefetch GEMM1 h fragments (global, own row)
  ushortx8 afh0 = *(const ushortx8*)(h_bf + (size_t)ncl * 64 + csub);
  ushortx8 afh1 = *(const ushortx8*)(h_bf + (size_t)ncl * 64 + 32 + csub);

  // ---- agg: 8 edges x 8 channel-groups in parallel, shfl-xor reduce ----
  int cg = lane & 7;
  for (int i = 0; i < 16; i++) {
    int rl = wv * 16 + i, node = n0b + rl;
    float pf[8] = {0.f, 0.f, 0.f, 0.f, 0.f, 0.f, 0.f, 0.f};
    if (node < NN) {
      int b = row_ptr[node], e = row_ptr[node + 1];
      for (int r = b + (lane >> 3); r < e; r += 8) {
        ushortx8 u = *(const ushortx8*)(emsg + (size_t)r * HD + cg * 8);
#pragma unroll
        for (int j = 0; j < 8; j++) pf[j] += bf2f(u[j]);
      }
    }
#pragma unroll
    for (int j = 0; j < 8; j++) {
      pf[j] += __shfl_xor(pf[j], 8);
      pf[j] += __shfl_xor(pf[j], 16);
      pf[j] += __shfl_xor(pf[j], 32);
    }
    if (lane < 8) {
      ushortx8 u;
#pragma unroll
      for (int j = 0; j < 8; j++) u[j] = f2bf(pf[j]);
      *(ushortx8*)(s_agg + rl * 128 + ((cg * 16) ^ ((rl & 7) << 4))) = u;
    }
  }
  __syncthreads();

  // ---- GEMM1: [h | agg] x wnm1 ----
  f32x4 acc[4];
#pragma unroll
  for (int n = 0; n < 4; n++) {
    float bv = s_b1[n * 16 + l15];
#pragma unroll
    for (int i = 0; i < 4; i++) acc[n][i] = bv;
  }
  ushortx8 af[4];
  af[0] = afh0; af[1] = afh1;
  af[2] = *(const ushortx8*)(s_agg + row_l * 128 + ((csub * 2) ^ rsw));
  af[3] = *(const ushortx8*)(s_agg + row_l * 128 + (((32 + csub) * 2) ^ rsw));
#pragma unroll
  for (int kk = 0; kk < 4; kk++) {
    bf16x8 av = __builtin_bit_cast(bf16x8, af[kk]);
#pragma unroll
    for (int n = 0; n < 4; n++) {
      int j = n * 16 + l15;
      ushortx8 bu = *(const ushortx8*)(s_w1 + j * 256 + (((kk * 32 + csub) * 2) ^ ((j & 7) << 4)));
      acc[n] = __builtin_amdgcn_mfma_f32_16x16x32_bf16(av, __builtin_bit_cast(bf16x8, bu), acc[n], 0, 0, 0);
    }
  }
#pragma unroll
  for (int n = 0; n < 4; n++) {
#pragma unroll
    for (int i = 0; i < 4; i++) {
      int r = wv * 16 + lq * 4 + i, col = n * 16 + l15;
      *(unsigned short*)(s_hid + r * 128 + ((col * 2) ^ ((r & 7) << 4))) = f2bf(fmaxf(acc[n][i], 0.f));
    }
  }
  // ---- GEMM2: hu = h(resid fp32) + b2 + hid x wnm2 ----
  f32x4 acc2[4];
#pragma unroll
  for (int n = 0; n < 4; n++) {
#pragma unroll
    for (int i = 0; i < 4; i++) {
      int r = wv * 16 + lq * 4 + i, col = n * 16 + l15;
      int rg = n0b + r; int rgc = rg < NN ? rg : NN - 1;
      acc2[n][i] = s_b2[col] + hbuf[(size_t)rgc * 64 + col];
    }
  }
#pragma unroll
  for (int kk = 0; kk < 2; kk++) {
    ushortx8 au = *(const ushortx8*)(s_hid + row_l * 128 + (((kk * 32 + csub) * 2) ^ rsw));
    bf16x8 av = __builtin_bit_cast(bf16x8, au);
#pragma unroll
    for (int n = 0; n < 4; n++) {
      int j = n * 16 + l15;
      ushortx8 bu = *(const ushortx8*)(s_w2 + j * 128 + (((kk * 32 + csub) * 2) ^ ((j & 7) << 4)));
      acc2[n] = __builtin_amdgcn_mfma_f32_16x16x32_bf16(av, __builtin_bit_cast(bf16x8, bu), acc2[n], 0, 0, 0);
    }
  }
#pragma unroll
  for (int n = 0; n < 4; n++) {
#pragma unroll
    for (int i = 0; i < 4; i++) {
      int r = wv * 16 + lq * 4 + i, col = n * 16 + l15;
      *(unsigned short*)(s_hid + r * 128 + ((col * 2) ^ ((r & 7) << 4))) = f2bf(acc2[n][i]);
    }
  }
  // ---- dec1 ----
  f32x4 acc3[4];
#pragma unroll
  for (int n = 0; n < 4; n++) {
    float bv = s_bd1[n * 16 + l15];
#pragma unroll
    for (int i = 0; i < 4; i++) acc3[n][i] = bv;
  }
#pragma unroll
  for (int kk = 0; kk < 2; kk++) {
    ushortx8 au = *(const ushortx8*)(s_hid + row_l * 128 + (((kk * 32 + csub) * 2) ^ rsw));
    bf16x8 av = __builtin_bit_cast(bf16x8, au);
#pragma unroll
    for (int n = 0; n < 4; n++) {
      int j = n * 16 + l15;
      ushortx8 bu = *(const ushortx8*)(s_wd1 + j * 128 + (((kk * 32 + csub) * 2) ^ ((j & 7) << 4)));
      acc3[n] = __builtin_amdgcn_mfma_f32_16x16x32_bf16(av, __builtin_bit_cast(bf16x8, bu), acc3[n], 0, 0, 0);
    }
  }
#pragma unroll
  for (int n = 0; n < 4; n++) {
#pragma unroll
    for (int i = 0; i < 4; i++) {
      int r = wv * 16 + lq * 4 + i, col = n * 16 + l15;
      *(unsigned short*)(s_hid + r * 128 + ((col * 2) ^ ((r & 7) << 4))) = f2bf(fmaxf(acc3[n][i], 0.f));
    }
  }
  // ---- dec2: per-lane partial over 16 channels, xor-reduce over lq groups ----
  ushortx8 u0 = *(const ushortx8*)(s_hid + row_l * 128 + ((lq * 32) ^ rsw));
  ushortx8 u1 = *(const ushortx8*)(s_hid + row_l * 128 + ((lq * 32 + 16) ^ rsw));
  float p[3] = {0.f, 0.f, 0.f};
#pragma unroll
  for (int i = 0; i < 8; i++) {
    float x0 = bf2f(u0[i]), x1 = bf2f(u1[i]);
    int c0 = lq * 16 + i, c1 = lq * 16 + 8 + i;
#pragma unroll
    for (int t = 0; t < 3; t++) p[t] += x0 * s_wd2[c0 * 3 + t] + x1 * s_wd2[c1 * 3 + t];
  }
#pragma unroll
  for (int t = 0; t < 3; t++) {
    p[t] += __shfl_xor(p[t], 16);
    p[t] += __shfl_xor(p[t], 32);
  }
  // ---- RK4 bookkeeping ----
  float dt = tspan[s + 1] - tspan[s];
  float o[3];
#pragma unroll
  for (int t = 0; t < 3; t++) o[t] = (p[t] + b_dec2[t]) * astd[t] + amean[t];
  const float ck = (k == 2) ? 1.0f : 0.5f;
  float vs[3] = {0.f, 0.f, 0.f};
  if (noderow < NN) {
    if (lq == 0) {
#pragma unroll
      for (int t = 0; t < 3; t++) {
        float v0v = V0[noderow * 3 + t];
        float wk = (k == 0 || k == 3) ? 1.f : 2.f;
        float va = (k == 0) ? o[t] : vacc[noderow * 3 + t] + wk * o[t];
        if (k < 3) {
          vacc[noderow * 3 + t] = va;
          vs[t] = v0v + ck * dt * o[t];
        } else {
          float vn = v0v + (dt / 6.f) * va;
          vel_next[noderow * 3 + t] = vn;
          vs[t] = vn;
        }
      }
    } else if (lq == 1) {
#pragma unroll
      for (int t = 0; t < 3; t++) {
        if (k < 3) {
          float v0v = V0[noderow * 3 + t];
          float vst = v0v + ck * dt * o[t];
          float pa;
          if (k == 0) pa = v0v + 2.f * vst;
          else pa = pacc[noderow * 3 + t] + ((k == 1) ? 2.f : 1.f) * vst;
          pacc[noderow * 3 + t] = pa;
        } else {
          pos_next[noderow * 3 + t] = pos_prev[noderow * 3 + t] + (dt / 6.f) * pacc[noderow * 3 + t];
        }
      }
    }
  }
  // ---- fused encoder for next stage (reads vs from lq==0 lanes) ----
  if (do_enc) {
    for (int i = 0; i < 16; i++) {
      int rl = wv * 16 + i, node = n0b + rl;
      float v0s = __shfl(vs[0], i);
      float v1s = __shfl(vs[1], i);
      float v2s = __shfl(vs[2], i);
      float hv = 0.f;
      if (node < NN) {
        float vn0 = (v0s - s_vm[0]) / s_vs[0];
        float vn1 = (v1s - s_vm[1]) / s_vs[1];
        float vn2 = (v2s - s_vm[2]) / s_vs[2];
        float a = h_pre[(size_t)node * 64 + lane] + vn0 * s_w1e[lane] + vn1 * s_w1e[64 + lane] + vn2 * s_w1e[128 + lane];
        hv = fmaxf(a, 0.f);
      }
      *(unsigned short*)(s_hid + rl * 128 + ((lane * 2) ^ ((rl & 7) << 4))) = f2bf(hv);
    }
    f32x4 ae[4];
#pragma unroll
    for (int n = 0; n < 4; n++) {
      float bv = s_be2[n * 16 + l15];
#pragma unroll
      for (int i = 0; i < 4; i++) ae[n][i] = bv;
    }
#pragma unroll
    for (int kk = 0; kk < 2; kk++) {
      ushortx8 au = *(const ushortx8*)(s_hid + row_l * 128 + (((kk * 32 + csub) * 2) ^ rsw));
      bf16x8 av = __builtin_bit_cast(bf16x8, au);
#pragma unroll
      for (int n = 0; n < 4; n++) {
        int j = n * 16 + l15;
        ushortx8 bu = *(const ushortx8*)(s_w2e + j * 128 + (((kk * 32 + csub) * 2) ^ ((j & 7) << 4)));
        ae[n] = __builtin_amdgcn_mfma_f32_16x16x32_bf16(av, __builtin_bit_cast(bf16x8, bu), ae[n], 0, 0, 0);
      }
    }
#pragma unroll
    for (int n = 0; n < 4; n++) {
#pragma unroll
      for (int i = 0; i < 4; i++) {
        int r = wv * 16 + lq * 4 + i, rowg = n0b + r, col = n * 16 + l15;
        if (rowg < NN) hbuf[(size_t)rowg * 64 + col] = ae[n][i];
        *(unsigned short*)(s_hid + r * 128 + ((col * 2) ^ ((r & 7) << 4))) = f2bf(ae[n][i]);
      }
    }
    if (noderow < NN) {
      ushortx8 q0 = *(const ushortx8*)(s_hid + row_l * 128 + ((lq * 32) ^ rsw));
      ushortx8 q1 = *(const ushortx8*)(s_hid + row_l * 128 + ((lq * 32 + 16) ^ rsw));
      ushortx8* op = (ushortx8*)(h_bf + (size_t)noderow * 64);
      op[lq * 2] = q0;
      op[lq * 2 + 1] = q1;
    }
  }
}

extern "C" void kernel_launch(void* const* d_in, const int* in_sizes, int n_in,
                              void* d_out, int out_size, void* d_ws, size_t ws_size,
                              hipStream_t stream) {
  (void)in_sizes; (void)n_in; (void)out_size; (void)ws_size;
  const float* world_pos = (const float*)d_in[0];
  const float* velocity  = (const float*)d_in[1];
  const int*   eidx      = (const int*)d_in[2];
  const float* eattr     = (const float*)d_in[3];
  const float* youngs    = (const float*)d_in[4];
  const float* onehot    = (const float*)d_in[5];
  const float* tspan     = (const float*)d_in[7];
  const float* ym        = (const float*)d_in[8];
  const float* ys        = (const float*)d_in[9];
  const float* emean     = (const float*)d_in[10];
  const float* estd      = (const float*)d_in[11];
  const float* vmean     = (const float*)d_in[12];
  const float* vstd      = (const float*)d_in[13];
  const float* amean     = (const float*)d_in[14];
  const float* astd      = (const float*)d_in[15];
  const float* w_ne1 = (const float*)d_in[16]; const float* b_ne1 = (const float*)d_in[17];
  const float* w_ne2 = (const float*)d_in[18]; const float* b_ne2 = (const float*)d_in[19];
  const float* w_ee1 = (const float*)d_in[20]; const float* b_ee1 = (const float*)d_in[21];
  const float* w_ee2 = (const float*)d_in[22]; const float* b_ee2 = (const float*)d_in[23];
  const float* w_em1 = (const float*)d_in[24]; const float* b_em1 = (const float*)d_in[25];
  const float* w_em2 = (const float*)d_in[26]; const float* b_em2 = (const float*)d_in[27];
  const float* w_nm1 = (const float*)d_in[28]; const float* b_nm1 = (const float*)d_in[29];
  const float* w_nm2 = (const float*)d_in[30]; const float* b_nm2 = (const float*)d_in[31];
  const float* w_dec1 = (const float*)d_in[32]; const float* b_dec1 = (const float*)d_in[33];
  const float* w_dec2 = (const float*)d_in[34]; const float* b_dec2 = (const float*)d_in[35];

  char* ws = (char*)d_ws;
  float* h_pre  = (float*)ws; ws += (size_t)NN * HD * 4;
  float* hbuf   = (float*)ws; ws += (size_t)NN * HD * 4;
  char* eenc_sw = ws; ws += (size_t)NE * 128;
  unsigned short* emsg_bf = (unsigned short*)ws; ws += (size_t)NE * HD * 2;
  unsigned short* h_bf    = (unsigned short*)ws; ws += (size_t)NN * HD * 2;
  char* w1em  = ws; ws += 64 * 384;
  char* w2em  = ws; ws += 64 * 128;
  char* wnm1s = ws; ws += 64 * 256;
  char* wnm2s = ws; ws += 64 * 128;
  char* wdec1s = ws; ws += 64 * 128;
  char* wne2s = ws; ws += 64 * 128;
  char* wee2s = ws; ws += 64 * 128;
  float* vacc = (float*)ws; ws += (size_t)NN * 3 * 4;
  float* pacc = (float*)ws; ws += (size_t)NN * 3 * 4;
  int* counts  = (int*)ws; ws += (size_t)NN * 4;
  int* fill    = (int*)ws; ws += (size_t)NN * 4;
  int* slot    = (int*)ws; ws += (size_t)NE * 4;
  int* row_ptr = (int*)ws; ws += (size_t)(NN + 1) * 4;

  float* PO = (float*)d_out;
  float* VO = PO + (size_t)TT * NN * 3;

  // --- once-per-launch precompute ---
  k_init_out<<<(NN * 3 + 255) / 256, 256, 0, stream>>>(world_pos, velocity, PO, VO);
  k_hpre<<<(NN * HD) / 256, 256, 0, stream>>>(youngs, onehot, ym, ys, w_ne1, b_ne1, h_pre);
  k_wprep_all<<<160, 256, 0, stream>>>(w_em1, w_em2, w_nm1, w_nm2, w_dec1, w_ne2, w_ee2,
                                       w1em, w2em, wnm1s, wnm2s, wdec1s, wne2s, wee2s);
  k_edge_enc_mfma<<<NE / 64, 256, 0, stream>>>(eattr, emean, estd, w_ee1, b_ee1, wee2s, b_ee2, eenc_sw);
  k_zero2<<<(NN + 255) / 256, 256, 0, stream>>>(counts, fill);
  k_count<<<NE / 256, 256, 0, stream>>>(eidx, counts);
  k_scan<<<1, 256, 0, stream>>>(counts, row_ptr);
  k_place<<<NE / 256, 256, 0, stream>>>(eidx, row_ptr, fill, slot);

  const int NBLK = (NN + 63) / 64;
  k_enc_mfma<<<NBLK, 256, 0, stream>>>(velocity, vmean, vstd, w_ne1, h_pre, wne2s, b_ne2, hbuf, h_bf);

  for (int s = 0; s < TT - 1; s++) {
    const float* V0 = VO + (size_t)s * NN * 3;
    const float* pos_prev = PO + (size_t)s * NN * 3;
    float* pos_next = PO + (size_t)(s + 1) * NN * 3;
    float* vel_next = VO + (size_t)(s + 1) * NN * 3;
    for (int k = 0; k < 4; k++) {
      k_edge_mfma<<<EDGE_GRID, 256, 0, stream>>>(eidx, slot, h_bf, eenc_sw, w1em, w2em,
                                                 b_em1, b_em2, emsg_bf);
      int do_enc = !(s == TT - 2 && k == 3);
      k_upd_enc<<<NBLK, 256, 0, stream>>>(row_ptr, emsg_bf, hbuf, h_bf,
                                          wnm1s, wnm2s, wdec1s, wne2s,
                                          b_nm1, b_nm2, b_dec1, b_dec2, w_dec2, amean, astd,
                                          w_ne1, h_pre, b_ne2, vmean, vstd,
                                          tspan, s, k, do_enc,
                                          V0, vacc, pacc, pos_prev, pos_next, vel_next);
    }
  }
}